// Round 6
// baseline (394.868 us; speedup 1.0000x reference)
//
#include <hip/hip_runtime.h>

// ---------------------------------------------------------------------------
// Types / helpers
// ---------------------------------------------------------------------------
typedef __bf16 bf16x8 __attribute__((ext_vector_type(8)));
typedef float  f32x4  __attribute__((ext_vector_type(4)));
typedef float  f32x16 __attribute__((ext_vector_type(16)));
typedef short  s16x8  __attribute__((ext_vector_type(8)));

__device__ __forceinline__ unsigned short f2b(float f) {
  unsigned int u = __float_as_uint(f);
  u += 0x7fffu + ((u >> 16) & 1u);           // round-to-nearest-even
  return (unsigned short)(u >> 16);
}
__device__ __forceinline__ float b2f(unsigned short h) {
  return __uint_as_float(((unsigned int)h) << 16);
}

__device__ __forceinline__ void gload_lds16(const unsigned short* g, unsigned short* l) {
  __builtin_amdgcn_global_load_lds((const __attribute__((address_space(1))) void*)g,
                                   (__attribute__((address_space(3))) void*)l, 16, 0, 0);
}

__device__ __forceinline__ void bar() {
  __builtin_amdgcn_sched_barrier(0);
  asm volatile("" ::: "memory");
  __builtin_amdgcn_s_barrier();
  asm volatile("" ::: "memory");
  __builtin_amdgcn_sched_barrier(0);
}

#define WAIT_LGKM0 do { asm volatile("s_waitcnt lgkmcnt(0)" ::: "memory"); \
                        __builtin_amdgcn_sched_barrier(0); } while (0)

// ---------------------------------------------------------------------------
// Weight transpose: in (R x C) f32 row-major  ->  out (C x R) bf16 row-major
// ---------------------------------------------------------------------------
__global__ __launch_bounds__(256) void transpose_w(const float* __restrict__ in,
                                                   unsigned short* __restrict__ out,
                                                   int R, int C) {
  __shared__ float t[32][33];
  int c0 = blockIdx.x * 32, r0 = blockIdx.y * 32;
  int tx = threadIdx.x & 31, ty = threadIdx.x >> 5;  // 32 x 8
  for (int i = ty; i < 32; i += 8)
    t[i][tx] = in[(size_t)(r0 + i) * C + (c0 + tx)];
  __syncthreads();
  for (int i = ty; i < 32; i += 8)
    out[(size_t)(c0 + i) * R + (r0 + tx)] = f2b(t[tx][i]);
}

// ---------------------------------------------------------------------------
// V transpose: V rows (4608 x vstride, d at cols 0..1023) -> Vt (8,1024,576)
// ---------------------------------------------------------------------------
__global__ __launch_bounds__(256) void transpose_v(const unsigned short* __restrict__ V,
                                                   unsigned short* __restrict__ Vt,
                                                   int vstride) {
  __shared__ unsigned short tile[64][72];
  const int t0 = blockIdx.x * 64;
  const int d0 = blockIdx.y * 64;
  const int b  = blockIdx.z;
  const int tid = threadIdx.x;
  const int r = tid >> 3, c8 = tid & 7;
#pragma unroll
  for (int p = 0; p < 2; ++p) {
    int row = p * 32 + r;
    s16x8 v = *(const s16x8*)(V + ((size_t)(b * 576 + t0 + row) * vstride + d0 + c8 * 8));
    *(s16x8*)&tile[row][c8 * 8] = v;
  }
  __syncthreads();
#pragma unroll
  for (int p = 0; p < 2; ++p) {
    int drow = p * 32 + r;
    unsigned short tmp[8];
#pragma unroll
    for (int j = 0; j < 8; ++j) tmp[j] = tile[c8 * 8 + j][drow];
    *(s16x8*)(Vt + ((size_t)(b * 1024 + d0 + drow) * 576 + t0 + c8 * 8)) = *(const s16x8*)tmp;
  }
}

// ---------------------------------------------------------------------------
// LayerNorm over last dim (f32 in -> bf16 out). One block per row, 256 thr.
// ---------------------------------------------------------------------------
__global__ __launch_bounds__(256) void ln_kernel(const float* __restrict__ in,
                                                 const float* __restrict__ g,
                                                 const float* __restrict__ b,
                                                 unsigned short* __restrict__ out,
                                                 int cols) {
  int row = blockIdx.x;
  const float* x = in + (size_t)row * cols;
  float s = 0.f, s2 = 0.f;
  for (int c = threadIdx.x * 4; c < cols; c += 1024) {
    float4 v = *(const float4*)(x + c);
    s  += v.x + v.y + v.z + v.w;
    s2 += v.x * v.x + v.y * v.y + v.z * v.z + v.w * v.w;
  }
#pragma unroll
  for (int o = 32; o > 0; o >>= 1) { s += __shfl_down(s, o); s2 += __shfl_down(s2, o); }
  __shared__ float rs[4], rs2[4];
  int w = threadIdx.x >> 6;
  if ((threadIdx.x & 63) == 0) { rs[w] = s; rs2[w] = s2; }
  __syncthreads();
  s  = rs[0] + rs[1] + rs[2] + rs[3];
  s2 = rs2[0] + rs2[1] + rs2[2] + rs2[3];
  float inv  = 1.f / (float)cols;
  float mean = s * inv;
  float var  = s2 * inv - mean * mean;
  float rstd = rsqrtf(var + 1e-5f);
  unsigned short* outp = out + (size_t)row * cols;
  for (int c = threadIdx.x * 4; c < cols; c += 1024) {
    float4 v = *(const float4*)(x + c);
    ushort4 ov;
    ov.x = f2b((v.x - mean) * rstd * g[c + 0] + b[c + 0]);
    ov.y = f2b((v.y - mean) * rstd * g[c + 1] + b[c + 1]);
    ov.z = f2b((v.z - mean) * rstd * g[c + 2] + b[c + 2]);
    ov.w = f2b((v.w - mean) * rstd * g[c + 3] + b[c + 3]);
    *(ushort4*)(outp + c) = ov;
  }
}

// ---------------------------------------------------------------------------
// 4-phase counted-vmcnt MFMA GEMM on v_mfma_f32_32x32x16_bf16.
// Tile BM x 256, BK=64, 8 waves (2M x 4N), per-wave output (BM/2) x 64.
// C/D layout (m74/m101): col = lane&31, row = (reg&3) + 8*(reg>>2) + 4*(lane>>5).
// A/B frags: lane row/col = lane&31, k = 8*(lane>>5) + j (same map both
// operands -> k-permutation cancels).
// Ring (round-4-verified slots): during tile t issue (t+1).A1 in p1,
// (t+2).B0 in p2, (t+2).B1 in p3, (t+2).A0 in p4.  Every current-buffer
// overwrite is behind a barrier following all waves' read-retire of that
// region.  Gate: vmcnt(6) LA=2 / vmcnt(5) LA=1; vmcnt(0) final tile.
// ---------------------------------------------------------------------------
template <int BM, int BIAS, int GELU, int RES, int OUTBF>
__global__ __launch_bounds__(512) void gemm256(const unsigned short* __restrict__ A,
                                               const unsigned short* __restrict__ Bt,
                                               float* __restrict__ Cf,
                                               unsigned short* __restrict__ Cb,
                                               const float* __restrict__ bias,
                                               const float* __restrict__ resf,
                                               const unsigned short* __restrict__ resb,
                                               int M, int N, int K) {
  constexpr int MF = BM / 64;   // per-wave 32-row m-frags (4 or 2)
  constexpr int MH = MF / 2;    // m-frags per phase-pair (2 or 1)
  constexpr int LA = BM / 128;  // gload_lds per wave per A-half (2 or 1)
  __shared__ unsigned short L[2][(BM + 256) * 64];
  const int tid = threadIdx.x;
  const int w = tid >> 6, l = tid & 63;
  const int l31 = l & 31, l5 = l >> 5;
  const int wm = w >> 2, wn = w & 3;
  const int m0 = blockIdx.x * BM, n0 = blockIdx.y * 256;
  const int NT = K >> 6;
  const int colsw = ((l & 7) ^ (l >> 3)) * 8;  // pre-swizzled source granule
  const int lrow = l >> 3;

  // half: 0=B0(rows n0..+128), 1=B1, 2=A0(rows m0..+BM/2), 3=A1
  auto stage = [&](int t, int half) {
    if (t >= NT) return;
    unsigned short* base = L[t & 1];
    if (half < 2) {
      const unsigned short* g = Bt + (size_t)(n0 + half * 128) * K + t * 64;
#pragma unroll
      for (int j = 0; j < 2; ++j) {
        int row = w * 16 + j * 8;
        gload_lds16(g + (size_t)(row + lrow) * K + colsw,
                    base + BM * 64 + half * 8192 + row * 64);
      }
    } else {
      const int h = half - 2;
      const unsigned short* g = A + (size_t)(m0 + h * (BM / 2)) * K + t * 64;
#pragma unroll
      for (int j = 0; j < LA; ++j) {
        int row = w * (8 * LA) + j * 8;
        gload_lds16(g + (size_t)(row + lrow) * K + colsw,
                    base + h * (BM / 2) * 64 + row * 64);
      }
    }
  };

  f32x16 acc[MF][2];
#pragma unroll
  for (int i = 0; i < MF; ++i)
#pragma unroll
    for (int j = 0; j < 2; ++j)
#pragma unroll
      for (int e = 0; e < 16; ++e) acc[i][j][e] = 0.f;

  // prologue: tile0 all 4 halves, tile1 first 3
  stage(0, 0); stage(0, 1); stage(0, 2); stage(0, 3);
  stage(1, 0); stage(1, 1); stage(1, 2);

  const int aoff = wm * (BM / 2) * 64;
  const int boff = BM * 64 + (wn >> 1) * 8192 + (wn & 1) * 64 * 64;
  const int swz = l31 & 7;

  for (int t = 0; t < NT; ++t) {
    const unsigned short* Lb = L[t & 1];
    // ---- gate: tile t fully landed; 3 halves (t+1/t+2) in flight ----
    if (t + 1 < NT) {
      if constexpr (LA == 2) asm volatile("s_waitcnt vmcnt(6)" ::: "memory");
      else                   asm volatile("s_waitcnt vmcnt(5)" ::: "memory");
    } else {
      asm volatile("s_waitcnt vmcnt(0)" ::: "memory");
    }
    __builtin_amdgcn_sched_barrier(0);
    bar();

    bf16x8 af[MH][4], bf[2][4];
    // ---- p1: read af-low + all bf; stage (t+1).A1; MFMA (m-low, nf0) ----
#pragma unroll
    for (int mf = 0; mf < MH; ++mf)
#pragma unroll
      for (int kf = 0; kf < 4; ++kf)
        af[mf][kf] = *(const bf16x8*)(Lb + aoff + (mf * 32 + l31) * 64 +
                                      (((kf * 2 + l5) ^ swz) * 8));
#pragma unroll
    for (int nf = 0; nf < 2; ++nf)
#pragma unroll
      for (int kf = 0; kf < 4; ++kf)
        bf[nf][kf] = *(const bf16x8*)(Lb + boff + (nf * 32 + l31) * 64 +
                                      (((kf * 2 + l5) ^ swz) * 8));
    stage(t + 1, 3);
    WAIT_LGKM0;
    __builtin_amdgcn_s_setprio(1);
#pragma unroll
    for (int kf = 0; kf < 4; ++kf)
#pragma unroll
      for (int mf = 0; mf < MH; ++mf)
        acc[mf][0] = __builtin_amdgcn_mfma_f32_32x32x16_bf16(af[mf][kf], bf[0][kf], acc[mf][0], 0, 0, 0);
    __builtin_amdgcn_s_setprio(0);
    bar();

    // ---- p2: stage (t+2).B0 (all B reads retired at p1 bar); MFMA (m-low, nf1) ----
    stage(t + 2, 0);
    __builtin_amdgcn_s_setprio(1);
#pragma unroll
    for (int kf = 0; kf < 4; ++kf)
#pragma unroll
      for (int mf = 0; mf < MH; ++mf)
        acc[mf][1] = __builtin_amdgcn_mfma_f32_32x32x16_bf16(af[mf][kf], bf[1][kf], acc[mf][1], 0, 0, 0);
    __builtin_amdgcn_s_setprio(0);
    bar();

    // ---- p3: read af-high; stage (t+2).B1; MFMA (m-high, nf0) ----
#pragma unroll
    for (int mf = 0; mf < MH; ++mf)
#pragma unroll
      for (int kf = 0; kf < 4; ++kf)
        af[mf][kf] = *(const bf16x8*)(Lb + aoff + ((MH + mf) * 32 + l31) * 64 +
                                      (((kf * 2 + l5) ^ swz) * 8));
    stage(t + 2, 1);
    WAIT_LGKM0;
    __builtin_amdgcn_s_setprio(1);
#pragma unroll
    for (int kf = 0; kf < 4; ++kf)
#pragma unroll
      for (int mf = 0; mf < MH; ++mf)
        acc[MH + mf][0] = __builtin_amdgcn_mfma_f32_32x32x16_bf16(af[mf][kf], bf[0][kf], acc[MH + mf][0], 0, 0, 0);
    __builtin_amdgcn_s_setprio(0);
    bar();

    // ---- p4: stage (t+2).A0 (A reads retired at p3 bar); MFMA (m-high, nf1) ----
    stage(t + 2, 2);
    __builtin_amdgcn_s_setprio(1);
#pragma unroll
    for (int kf = 0; kf < 4; ++kf)
#pragma unroll
      for (int mf = 0; mf < MH; ++mf)
        acc[MH + mf][1] = __builtin_amdgcn_mfma_f32_32x32x16_bf16(af[mf][kf], bf[1][kf], acc[MH + mf][1], 0, 0, 0);
    __builtin_amdgcn_s_setprio(0);
  }

  bar();  // all frag reads retired -> both LDS buffers free for patches

  // ---- epilogue: per-wave 32x64 patch in LDS, vectorized coalesced stores ----
  float bias_v[2];
  if (BIAS) {
#pragma unroll
    for (int nf = 0; nf < 2; ++nf) bias_v[nf] = bias[n0 + wn * 64 + nf * 32 + l31];
  }
  unsigned short* patch  = ((unsigned short*)L) + w * (32 * 72);
  float*          patchf = ((float*)L) + w * (32 * 68);

#pragma unroll
  for (int mf = 0; mf < MF; ++mf) {
#pragma unroll
    for (int nf = 0; nf < 2; ++nf) {
#pragma unroll
      for (int r = 0; r < 16; ++r) {
        float v = acc[mf][nf][r];
        if (BIAS) v += bias_v[nf];
        if (GELU) {
          float t2 = 1.5957691f * (v + 0.044715f * v * v * v);  // 2*z
          float e = __expf(fminf(t2, 60.f));
          v = v * e / (e + 1.f);
        }
        int prow = (r & 3) + 8 * (r >> 2) + 4 * l5;
        int pcol = nf * 32 + l31;
        if (OUTBF) patch[prow * 72 + pcol] = f2b(v);
        else       patchf[prow * 68 + pcol] = v;
      }
    }
    WAIT_LGKM0;  // patch writes visible to own wave before transpose read
    if (OUTBF) {
      // 32 rows x 64 cols bf16: 4 x s16x8 per lane, 8 lanes cover one row
#pragma unroll
      for (int half = 0; half < 4; ++half) {
        int prow = half * 8 + (l >> 3);
        int pcol = (l & 7) * 8;
        s16x8 vv = *(const s16x8*)(patch + prow * 72 + pcol);
        int grow = m0 + wm * (BM / 2) + mf * 32 + prow;
        int gcol = n0 + wn * 64 + pcol;
        *(s16x8*)(Cb + (size_t)grow * N + gcol) = vv;
      }
    } else {
      // 32 rows x 64 cols f32: 8 x float4 per lane, 16 lanes cover one row
#pragma unroll
      for (int p = 0; p < 8; ++p) {
        int prow = p * 4 + (l >> 4);
        int pcol = (l & 15) * 4;
        float4 vv = *(const float4*)(patchf + prow * 68 + pcol);
        int grow = m0 + wm * (BM / 2) + mf * 32 + prow;
        int gcol = n0 + wn * 64 + pcol;
        if (RES == 1) {
          float4 rv = *(const float4*)(resf + (size_t)grow * N + gcol);
          vv.x += rv.x; vv.y += rv.y; vv.z += rv.z; vv.w += rv.w;
        }
        if (RES == 2) {
          ushort4 rv = *(const ushort4*)(resb + (size_t)grow * N + gcol);
          vv.x += b2f(rv.x); vv.y += b2f(rv.y); vv.z += b2f(rv.z); vv.w += b2f(rv.w);
        }
        *(float4*)(Cf + (size_t)grow * N + gcol) = vv;
      }
    }
    WAIT_LGKM0;  // reads done before next mf overwrites patch
  }
}

// ---------------------------------------------------------------------------
// MFMA flash attention (unchanged from round 4).
// ---------------------------------------------------------------------------
__global__ __launch_bounds__(256) void attn_mfma(const unsigned short* __restrict__ Qb,
                                                 const unsigned short* __restrict__ Kb,
                                                 const unsigned short* __restrict__ Vtb,
                                                 unsigned short* __restrict__ Ob,
                                                 int kstride) {
  __shared__ unsigned short Qs[64 * 64];
  __shared__ unsigned short Ks[2][64 * 64];
  __shared__ unsigned short Vs[2][64 * 64];
  __shared__ unsigned short Ps[64 * 64];

  const int t = threadIdx.x, w = t >> 6, l = t & 63;
  const int b = blockIdx.z, h = blockIdx.y, q0 = blockIdx.x * 64;
  const int rl = l & 15, kb = l >> 4;

  auto stage64 = [&](unsigned short* lds, const unsigned short* g, int gstride) {
#pragma unroll
    for (int p = 0; p < 2; ++p) {
      int row = p * 32 + w * 8 + (l >> 3);
      const unsigned short* src = g + (size_t)row * gstride + (((l & 7) ^ (row & 7)) * 8);
      gload_lds16(src, lds + p * 2048 + w * 512);
    }
  };

  const unsigned short* Qg = Qb + ((size_t)(b * 1024 + q0) * 1024 + h * 64);
  auto Kg = [&](int kt) { return Kb + ((size_t)(b * 576 + kt * 64) * kstride + h * 64); };
  auto Vg = [&](int kt) { return Vtb + ((size_t)(b * 1024 + h * 64) * 576 + kt * 64); };

  stage64(Qs, Qg, 1024);
  stage64(Ks[0], Kg(0), kstride);
  stage64(Vs[0], Vg(0), 576);
  __syncthreads();

  bf16x8 qf[2];
  {
    int row = w * 16 + rl;
#pragma unroll
    for (int kf = 0; kf < 2; ++kf)
      qf[kf] = *(const bf16x8*)(Qs + row * 64 + (((kf * 4 + kb) ^ (row & 7)) * 8));
  }

  float m_run[4], l_run[4];
  f32x4 accO[4];
#pragma unroll
  for (int r = 0; r < 4; ++r) { m_run[r] = -1e30f; l_run[r] = 0.f; }
  f32x4 zz = {0.f, 0.f, 0.f, 0.f};
#pragma unroll
  for (int nf = 0; nf < 4; ++nf) accO[nf] = zz;

  for (int kt = 0; kt < 9; ++kt) {
    const int buf = kt & 1;
    if (kt + 1 < 9) {
      stage64(Ks[buf ^ 1], Kg(kt + 1), kstride);
      stage64(Vs[buf ^ 1], Vg(kt + 1), 576);
    }

    f32x4 accS[4];
#pragma unroll
    for (int nf = 0; nf < 4; ++nf) accS[nf] = zz;
#pragma unroll
    for (int nf = 0; nf < 4; ++nf) {
      int row = nf * 16 + rl;
#pragma unroll
      for (int kf = 0; kf < 2; ++kf) {
        bf16x8 kfrag = *(const bf16x8*)(Ks[buf] + row * 64 + (((kf * 4 + kb) ^ (row & 7)) * 8));
        accS[nf] = __builtin_amdgcn_mfma_f32_16x16x32_bf16(qf[kf], kfrag, accS[nf], 0, 0, 0);
      }
    }

    float sv[4][4];
#pragma unroll
    for (int nf = 0; nf < 4; ++nf)
#pragma unroll
      for (int r = 0; r < 4; ++r) sv[nf][r] = accS[nf][r] * 0.125f;

    float al[4];
#pragma unroll
    for (int r = 0; r < 4; ++r) {
      float mr = fmaxf(fmaxf(sv[0][r], sv[1][r]), fmaxf(sv[2][r], sv[3][r]));
#pragma unroll
      for (int xm = 1; xm < 16; xm <<= 1) mr = fmaxf(mr, __shfl_xor(mr, xm));
      float mn = fmaxf(m_run[r], mr);
      al[r] = __expf(m_run[r] - mn);
      m_run[r] = mn;
      float rs = 0.f;
#pragma unroll
      for (int nf = 0; nf < 4; ++nf) {
        sv[nf][r] = __expf(sv[nf][r] - mn);
        rs += sv[nf][r];
      }
#pragma unroll
      for (int xm = 1; xm < 16; xm <<= 1) rs += __shfl_xor(rs, xm);
      l_run[r] = l_run[r] * al[r] + rs;
    }

#pragma unroll
    for (int nf = 0; nf < 4; ++nf)
#pragma unroll
      for (int r = 0; r < 4; ++r) {
        int q = w * 16 + kb * 4 + r;
        int col = nf * 16 + rl;
        Ps[q * 64 + (col ^ ((q & 7) << 3))] = f2b(sv[nf][r]);
      }

#pragma unroll
    for (int nf = 0; nf < 4; ++nf)
#pragma unroll
      for (int r = 0; r < 4; ++r) accO[nf][r] *= al[r];

    asm volatile("s_waitcnt lgkmcnt(0)" ::: "memory");
    __builtin_amdgcn_sched_barrier(0);

    bf16x8 pf[2];
    {
      int row = w * 16 + rl;
#pragma unroll
      for (int kf = 0; kf < 2; ++kf)
        pf[kf] = *(const bf16x8*)(Ps + row * 64 + (((kf * 4 + kb) ^ (row & 7)) * 8));
    }
#pragma unroll
    for (int nf = 0; nf < 4; ++nf) {
      int row = nf * 16 + rl;
#pragma unroll
      for (int kf = 0; kf < 2; ++kf) {
        bf16x8 vfrag = *(const bf16x8*)(Vs[buf] + row * 64 + (((kf * 4 + kb) ^ (row & 7)) * 8));
        accO[nf] = __builtin_amdgcn_mfma_f32_16x16x32_bf16(pf[kf], vfrag, accO[nf], 0, 0, 0);
      }
    }

    __syncthreads();
  }

#pragma unroll
  for (int nf = 0; nf < 4; ++nf) {
#pragma unroll
    for (int r = 0; r < 4; ++r) {
      float o = accO[nf][r] / l_run[r];
      size_t qg = (size_t)(b * 1024 + q0 + w * 16 + kb * 4 + r);
      Ob[qg * 1024 + h * 64 + nf * 16 + rl] = f2b(o);
    }
  }
}

// ---------------------------------------------------------------------------
// Launch
// ---------------------------------------------------------------------------
extern "C" void kernel_launch(void* const* d_in, const int* in_sizes, int n_in,
                              void* d_out, int out_size, void* d_ws, size_t ws_size,
                              hipStream_t stream) {
  const float* grid_in = (const float*)d_in[0];
  const float* qpos    = (const float*)d_in[1];
  const float* Wq      = (const float*)d_in[2];
  const float* Wk      = (const float*)d_in[3];
  const float* Wv      = (const float*)d_in[4];
  const float* Wo      = (const float*)d_in[5];
  const float* g_grid  = (const float*)d_in[6];
  const float* b_grid  = (const float*)d_in[7];
  const float* g_q     = (const float*)d_in[8];
  const float* b_q     = (const float*)d_in[9];
  const float* g_mlp   = (const float*)d_in[10];
  const float* b_mlp   = (const float*)d_in[11];
  const float* W1      = (const float*)d_in[12];
  const float* b1      = (const float*)d_in[13];
  const float* W2      = (const float*)d_in[14];
  const float* b2      = (const float*)d_in[15];

  char* ws = (char*)d_ws;
  size_t off = 0;
  auto alloc = [&](size_t bytes) -> void* {
    void* p = ws + off;
    off = (off + bytes + 255) & ~(size_t)255;
    return p;
  };

  unsigned short* Wqt  = (unsigned short*)alloc((size_t)1024 * 512 * 2);
  unsigned short* Wkvt = (unsigned short*)alloc((size_t)2048 * 1024 * 2);  // [Wk^T ; Wv^T]
  unsigned short* Wot  = (unsigned short*)alloc((size_t)1024 * 1024 * 2);
  unsigned short* W1t  = (unsigned short*)alloc((size_t)4096 * 1024 * 2);
  unsigned short* W2t  = (unsigned short*)alloc((size_t)1024 * 4096 * 2);
  unsigned short* gn   = (unsigned short*)alloc((size_t)4608 * 1024 * 2);
  unsigned short* qn   = (unsigned short*)alloc((size_t)8192 * 512 * 2);
  unsigned short* KVb  = (unsigned short*)alloc((size_t)4608 * 2048 * 2);  // K|V interleaved
  unsigned short* Qbf  = (unsigned short*)alloc((size_t)8192 * 1024 * 2);
  unsigned short* atb  = (unsigned short*)alloc((size_t)8192 * 1024 * 2);
  float*          xf   = (float*)alloc((size_t)8192 * 1024 * 4);
  unsigned short* xnb  = (unsigned short*)alloc((size_t)8192 * 1024 * 2);
  unsigned short* hb   = (unsigned short*)alloc((size_t)8192 * 4096 * 2);
  unsigned short* Vtb  = hb;  // dead before W1 GEMM writes hb (stream-ordered)
  (void)ws_size; (void)in_sizes; (void)n_in; (void)out_size;

  // weight transposes (f32 -> bf16, N-major)
  transpose_w<<<dim3(32, 16), 256, 0, stream>>>(Wq, Wqt, 512, 1024);
  transpose_w<<<dim3(32, 32), 256, 0, stream>>>(Wk, Wkvt, 1024, 1024);
  transpose_w<<<dim3(32, 32), 256, 0, stream>>>(Wv, Wkvt + (size_t)1024 * 1024, 1024, 1024);
  transpose_w<<<dim3(32, 32), 256, 0, stream>>>(Wo, Wot, 1024, 1024);
  transpose_w<<<dim3(128, 32), 256, 0, stream>>>(W1, W1t, 1024, 4096);
  transpose_w<<<dim3(32, 128), 256, 0, stream>>>(W2, W2t, 4096, 1024);

  // layernorms
  ln_kernel<<<4608, 256, 0, stream>>>(grid_in, g_grid, b_grid, gn, 1024);
  ln_kernel<<<8192, 256, 0, stream>>>(qpos, g_q, b_q, qn, 512);

  // fused K|V projection: (4608 x 2048) = gn @ [Wk Wv]
  gemm256<128, 0, 0, 0, 1><<<dim3(36, 8), 512, 0, stream>>>(gn, Wkvt, nullptr, KVb, nullptr, nullptr, nullptr, 4608, 2048, 1024);
  // Q projection (bf16 only)
  gemm256<128, 0, 0, 0, 1><<<dim3(64, 4), 512, 0, stream>>>(qn, Wqt, nullptr, Qbf, nullptr, nullptr, nullptr, 8192, 1024, 512);

  // V transpose for PV B-operand (V half of KVb)
  transpose_v<<<dim3(9, 16, 8), 256, 0, stream>>>(KVb + 1024, Vtb, 2048);

  // attention (MFMA)
  attn_mfma<<<dim3(16, 16, 8), 256, 0, stream>>>(Qbf, KVb, Vtb, atb, 2048);

  // x = Q + attn @ Wo   (residual read as bf16)
  gemm256<128, 0, 0, 2, 0><<<dim3(64, 4), 512, 0, stream>>>(atb, Wot, xf, nullptr, nullptr, nullptr, Qbf, 8192, 1024, 1024);

  // MLP
  ln_kernel<<<8192, 256, 0, stream>>>(xf, g_mlp, b_mlp, xnb, 1024);
  gemm256<256, 1, 1, 0, 1><<<dim3(32, 16), 512, 0, stream>>>(xnb, W1t, nullptr, hb, b1, nullptr, nullptr, 8192, 4096, 1024);
  gemm256<128, 1, 0, 1, 0><<<dim3(64, 4), 512, 0, stream>>>(hb, W2t, (float*)d_out, nullptr, b2, xf, nullptr, 8192, 1024, 4096);
}

// Round 7
// 351.479 us; speedup vs baseline: 1.1234x; 1.1234x over previous
//
#include <hip/hip_runtime.h>

// ---------------------------------------------------------------------------
// Types / helpers
// ---------------------------------------------------------------------------
typedef __bf16 bf16x8 __attribute__((ext_vector_type(8)));
typedef float  f32x4  __attribute__((ext_vector_type(4)));
typedef short  s16x8  __attribute__((ext_vector_type(8)));

__device__ __forceinline__ unsigned short f2b(float f) {
  unsigned int u = __float_as_uint(f);
  u += 0x7fffu + ((u >> 16) & 1u);           // round-to-nearest-even
  return (unsigned short)(u >> 16);
}
__device__ __forceinline__ float b2f(unsigned short h) {
  return __uint_as_float(((unsigned int)h) << 16);
}

__device__ __forceinline__ void gload_lds16(const unsigned short* g, unsigned short* l) {
  __builtin_amdgcn_global_load_lds((const __attribute__((address_space(1))) void*)g,
                                   (__attribute__((address_space(3))) void*)l, 16, 0, 0);
}

__device__ __forceinline__ void bar() {
  __builtin_amdgcn_sched_barrier(0);
  asm volatile("" ::: "memory");
  __builtin_amdgcn_s_barrier();
  asm volatile("" ::: "memory");
  __builtin_amdgcn_sched_barrier(0);
}

#define WAIT_LGKM0 do { asm volatile("s_waitcnt lgkmcnt(0)" ::: "memory"); \
                        __builtin_amdgcn_sched_barrier(0); } while (0)

// ---------------------------------------------------------------------------
// Weight transpose: in (R x C) f32 row-major  ->  out (C x R) bf16 row-major
// ---------------------------------------------------------------------------
__global__ __launch_bounds__(256) void transpose_w(const float* __restrict__ in,
                                                   unsigned short* __restrict__ out,
                                                   int R, int C) {
  __shared__ float t[32][33];
  int c0 = blockIdx.x * 32, r0 = blockIdx.y * 32;
  int tx = threadIdx.x & 31, ty = threadIdx.x >> 5;  // 32 x 8
  for (int i = ty; i < 32; i += 8)
    t[i][tx] = in[(size_t)(r0 + i) * C + (c0 + tx)];
  __syncthreads();
  for (int i = ty; i < 32; i += 8)
    out[(size_t)(c0 + i) * R + (r0 + tx)] = f2b(t[tx][i]);
}

// ---------------------------------------------------------------------------
// LayerNorm over last dim (f32 in -> bf16 out). One block per row, 256 thr.
// ---------------------------------------------------------------------------
__global__ __launch_bounds__(256) void ln_kernel(const float* __restrict__ in,
                                                 const float* __restrict__ g,
                                                 const float* __restrict__ b,
                                                 unsigned short* __restrict__ out,
                                                 int cols) {
  int row = blockIdx.x;
  const float* x = in + (size_t)row * cols;
  float s = 0.f, s2 = 0.f;
  for (int c = threadIdx.x * 4; c < cols; c += 1024) {
    float4 v = *(const float4*)(x + c);
    s  += v.x + v.y + v.z + v.w;
    s2 += v.x * v.x + v.y * v.y + v.z * v.z + v.w * v.w;
  }
#pragma unroll
  for (int o = 32; o > 0; o >>= 1) { s += __shfl_down(s, o); s2 += __shfl_down(s2, o); }
  __shared__ float rs[4], rs2[4];
  int w = threadIdx.x >> 6;
  if ((threadIdx.x & 63) == 0) { rs[w] = s; rs2[w] = s2; }
  __syncthreads();
  s  = rs[0] + rs[1] + rs[2] + rs[3];
  s2 = rs2[0] + rs2[1] + rs2[2] + rs2[3];
  float inv  = 1.f / (float)cols;
  float mean = s * inv;
  float var  = s2 * inv - mean * mean;
  float rstd = rsqrtf(var + 1e-5f);
  unsigned short* outp = out + (size_t)row * cols;
  for (int c = threadIdx.x * 4; c < cols; c += 1024) {
    float4 v = *(const float4*)(x + c);
    ushort4 ov;
    ov.x = f2b((v.x - mean) * rstd * g[c + 0] + b[c + 0]);
    ov.y = f2b((v.y - mean) * rstd * g[c + 1] + b[c + 1]);
    ov.z = f2b((v.z - mean) * rstd * g[c + 2] + b[c + 2]);
    ov.w = f2b((v.w - mean) * rstd * g[c + 3] + b[c + 3]);
    *(ushort4*)(outp + c) = ov;
  }
}

// ---------------------------------------------------------------------------
// 4-phase counted-vmcnt MFMA GEMM body (round-4-verified, 16x16x32 bf16).
// Tile BM x 256, BK=64, 8 waves (2M x 4N), per-wave output (BM/2) x 64.
// RES: 0=none, 1=f32, 2=bf16.  OUTBF: 1=bf16 out, 0=f32 out.
// L: shared, 2*(BM+256)*64 shorts.  NT must be even (patch reuses L).
// ---------------------------------------------------------------------------
template <int BM, int BIAS, int GELU, int RES, int OUTBF>
__device__ __forceinline__ void gemm_body(const unsigned short* __restrict__ A,
                                          const unsigned short* __restrict__ Bt,
                                          float* __restrict__ Cf,
                                          unsigned short* __restrict__ Cb,
                                          const float* __restrict__ bias,
                                          const float* __restrict__ resf,
                                          const unsigned short* __restrict__ resb,
                                          int N, int K, int m0, int n0,
                                          unsigned short* L) {
  constexpr int MF = BM / 32;   // per-wave M frags (8 or 4)
  constexpr int MH = MF / 2;
  constexpr int LA = BM / 128;  // gload_lds per wave per A-half (2 or 1)
  constexpr int LSTEP = (BM + 256) * 64;
  const int tid = threadIdx.x;
  const int w = tid >> 6, l = tid & 63;
  const int rl = l & 15, kb = l >> 4;
  const int wm = w >> 2, wn = w & 3;
  const int NT = K >> 6;
  const int colsw = ((l & 7) ^ (l >> 3)) * 8;  // pre-swizzled source granule
  const int lrow = l >> 3;

  // half: 0=B0(rows n0..+128), 1=B1, 2=A0(rows m0..+BM/2), 3=A1
  auto stage = [&](int t, int half) {
    if (t >= NT) return;
    unsigned short* base = L + (t & 1) * LSTEP;
    if (half < 2) {
      const unsigned short* g = Bt + (size_t)(n0 + half * 128) * K + t * 64;
#pragma unroll
      for (int j = 0; j < 2; ++j) {
        int row = w * 16 + j * 8;
        gload_lds16(g + (size_t)(row + lrow) * K + colsw,
                    base + BM * 64 + half * 8192 + row * 64);
      }
    } else {
      const int h = half - 2;
      const unsigned short* g = A + (size_t)(m0 + h * (BM / 2)) * K + t * 64;
#pragma unroll
      for (int j = 0; j < LA; ++j) {
        int row = w * (8 * LA) + j * 8;
        gload_lds16(g + (size_t)(row + lrow) * K + colsw,
                    base + h * (BM / 2) * 64 + row * 64);
      }
    }
  };

  f32x4 acc[MF][4];
  f32x4 zz = {0.f, 0.f, 0.f, 0.f};
#pragma unroll
  for (int i = 0; i < MF; ++i)
#pragma unroll
    for (int j = 0; j < 4; ++j) acc[i][j] = zz;

  // prologue: tile0 all 4 halves, tile1 first 3
  stage(0, 0); stage(0, 1); stage(0, 2); stage(0, 3);
  stage(1, 0); stage(1, 1); stage(1, 2);

  const int aoff = wm * (BM / 2) * 64;
  const int boff = BM * 64 + (wn >> 1) * 8192 + (wn & 1) * 64 * 64;

  for (int t = 0; t < NT; ++t) {
    const unsigned short* Lb = L + (t & 1) * LSTEP;
    // ---- gate: tile t fully landed; 3 halves (t+1/t+2) in flight ----
    if (t + 1 < NT) {
      if constexpr (LA == 2) asm volatile("s_waitcnt vmcnt(6)" ::: "memory");
      else                   asm volatile("s_waitcnt vmcnt(5)" ::: "memory");
    } else {
      asm volatile("s_waitcnt vmcnt(0)" ::: "memory");
    }
    __builtin_amdgcn_sched_barrier(0);
    bar();

    bf16x8 af[MH][2], bf[4][2];
    // ---- p1: read all B + lower A; stage (t+1).A1; MFMA q0 ----
#pragma unroll
    for (int mf = 0; mf < MH; ++mf)
#pragma unroll
      for (int kf = 0; kf < 2; ++kf)
        af[mf][kf] = *(const bf16x8*)(Lb + aoff + (mf * 16 + rl) * 64 +
                                      (((kf * 4 + kb) ^ (rl & 7)) * 8));
#pragma unroll
    for (int nf = 0; nf < 4; ++nf)
#pragma unroll
      for (int kf = 0; kf < 2; ++kf)
        bf[nf][kf] = *(const bf16x8*)(Lb + boff + (nf * 16 + rl) * 64 +
                                      (((kf * 4 + kb) ^ (rl & 7)) * 8));
    stage(t + 1, 3);
    WAIT_LGKM0;
    __builtin_amdgcn_s_setprio(1);
#pragma unroll
    for (int mf = 0; mf < MH; ++mf)
#pragma unroll
      for (int nf = 0; nf < 2; ++nf)
#pragma unroll
        for (int kf = 0; kf < 2; ++kf)
          acc[mf][nf] = __builtin_amdgcn_mfma_f32_16x16x32_bf16(af[mf][kf], bf[nf][kf], acc[mf][nf], 0, 0, 0);
    __builtin_amdgcn_s_setprio(0);
    bar();

    // ---- p2: stage (t+2).B0; MFMA q1 ----
    stage(t + 2, 0);
    __builtin_amdgcn_s_setprio(1);
#pragma unroll
    for (int mf = 0; mf < MH; ++mf)
#pragma unroll
      for (int nf = 2; nf < 4; ++nf)
#pragma unroll
        for (int kf = 0; kf < 2; ++kf)
          acc[mf][nf] = __builtin_amdgcn_mfma_f32_16x16x32_bf16(af[mf][kf], bf[nf][kf], acc[mf][nf], 0, 0, 0);
    __builtin_amdgcn_s_setprio(0);
    bar();

    // ---- p3: read upper A; stage (t+2).B1; MFMA q2 ----
#pragma unroll
    for (int mf = 0; mf < MH; ++mf)
#pragma unroll
      for (int kf = 0; kf < 2; ++kf)
        af[mf][kf] = *(const bf16x8*)(Lb + aoff + ((MH + mf) * 16 + rl) * 64 +
                                      (((kf * 4 + kb) ^ (rl & 7)) * 8));
    stage(t + 2, 1);
    WAIT_LGKM0;
    __builtin_amdgcn_s_setprio(1);
#pragma unroll
    for (int mf = 0; mf < MH; ++mf)
#pragma unroll
      for (int nf = 0; nf < 2; ++nf)
#pragma unroll
        for (int kf = 0; kf < 2; ++kf)
          acc[MH + mf][nf] = __builtin_amdgcn_mfma_f32_16x16x32_bf16(af[mf][kf], bf[nf][kf], acc[MH + mf][nf], 0, 0, 0);
    __builtin_amdgcn_s_setprio(0);
    bar();

    // ---- p4: stage (t+2).A0; MFMA q3 ----
    stage(t + 2, 2);
    __builtin_amdgcn_s_setprio(1);
#pragma unroll
    for (int mf = 0; mf < MH; ++mf)
#pragma unroll
      for (int nf = 2; nf < 4; ++nf)
#pragma unroll
        for (int kf = 0; kf < 2; ++kf)
          acc[MH + mf][nf] = __builtin_amdgcn_mfma_f32_16x16x32_bf16(af[mf][kf], bf[nf][kf], acc[MH + mf][nf], 0, 0, 0);
    __builtin_amdgcn_s_setprio(0);
  }

  bar();  // all frag reads done; L free for epilogue patches (NT even)

  // ---- epilogue: per-wave 16x72 patch in LDS, vectorized stores ----
  float bias_v[4];
  if (BIAS) {
#pragma unroll
    for (int nf = 0; nf < 4; ++nf) bias_v[nf] = bias[n0 + wn * 64 + nf * 16 + rl];
  }
  unsigned short* patch  = L + w * (16 * 72);
  float*          patchf = ((float*)L) + w * (16 * 72);

#pragma unroll
  for (int mf = 0; mf < MF; ++mf) {
#pragma unroll
    for (int nf = 0; nf < 4; ++nf) {
#pragma unroll
      for (int r = 0; r < 4; ++r) {
        float v = acc[mf][nf][r];
        if (BIAS) v += bias_v[nf];
        if (GELU) {
          float t2 = 1.5957691f * (v + 0.044715f * v * v * v);  // 2*z
          float e = __expf(fminf(t2, 60.f));
          v = v * e / (e + 1.f);
        }
        int prow = kb * 4 + r, pcol = nf * 16 + rl;
        if (OUTBF) patch[prow * 72 + pcol] = f2b(v);
        else       patchf[prow * 72 + pcol] = v;
      }
    }
    WAIT_LGKM0;  // patch writes visible to own wave before transpose read
    if (OUTBF) {
#pragma unroll
      for (int half = 0; half < 2; ++half) {
        int prow = half * 8 + (l >> 3);
        int pcol = (l & 7) * 8;
        s16x8 vv = *(const s16x8*)(patch + prow * 72 + pcol);
        int grow = m0 + wm * (BM / 2) + mf * 16 + prow;
        int gcol = n0 + wn * 64 + pcol;
        *(s16x8*)(Cb + (size_t)grow * N + gcol) = vv;
      }
    } else {
#pragma unroll
      for (int p = 0; p < 4; ++p) {
        int prow = p * 4 + (l >> 4);
        int pcol = (l & 15) * 4;
        float4 vv = *(const float4*)(patchf + prow * 72 + pcol);
        int grow = m0 + wm * (BM / 2) + mf * 16 + prow;
        int gcol = n0 + wn * 64 + pcol;
        if (RES == 1) {
          float4 rv = *(const float4*)(resf + (size_t)grow * N + gcol);
          vv.x += rv.x; vv.y += rv.y; vv.z += rv.z; vv.w += rv.w;
        }
        if (RES == 2) {
          ushort4 rv = *(const ushort4*)(resb + (size_t)grow * N + gcol);
          vv.x += b2f(rv.x); vv.y += b2f(rv.y); vv.z += b2f(rv.z); vv.w += b2f(rv.w);
        }
        *(float4*)(Cf + (size_t)grow * N + gcol) = vv;
      }
    }
    WAIT_LGKM0;  // reads done before next mf overwrites patch
  }
}

// Generic single-GEMM wrapper
template <int BM, int BIAS, int GELU, int RES, int OUTBF>
__global__ __launch_bounds__(512) void gemm256(const unsigned short* __restrict__ A,
                                               const unsigned short* __restrict__ Bt,
                                               float* __restrict__ Cf,
                                               unsigned short* __restrict__ Cb,
                                               const float* __restrict__ bias,
                                               const float* __restrict__ resf,
                                               const unsigned short* __restrict__ resb,
                                               int N, int K) {
  __shared__ unsigned short L[2 * (BM + 256) * 64];
  gemm_body<BM, BIAS, GELU, RES, OUTBF>(A, Bt, Cf, Cb, bias, resf, resb, N, K,
                                        blockIdx.x * BM, blockIdx.y * 256, L);
}

// ---------------------------------------------------------------------------
// Fused K / V^T / Q projection dispatch: 544 blocks.
//   x <  144: K   = gn @ Wk      (M=4608, N=1024, K=1024), grid 36x4
//   x <  288: V^T = Wv^T @ gn^T  (M=1024, N=4608, K=1024), grid 8x18
//   else    : Q   = qn @ Wq      (M=8192, N=1024, K=512),  grid 64x4
// ---------------------------------------------------------------------------
__global__ __launch_bounds__(512) void kvq_gemm(const unsigned short* __restrict__ gn,
                                                const unsigned short* __restrict__ Wkt,
                                                unsigned short* __restrict__ Kb,
                                                const unsigned short* __restrict__ Wvt,
                                                unsigned short* __restrict__ Vt2,
                                                const unsigned short* __restrict__ qn,
                                                const unsigned short* __restrict__ Wqt,
                                                unsigned short* __restrict__ Qbf) {
  __shared__ unsigned short L[2 * (128 + 256) * 64];
  const int x = blockIdx.x;
  if (x < 144) {
    gemm_body<128, 0, 0, 0, 1>(gn, Wkt, nullptr, Kb, nullptr, nullptr, nullptr,
                               1024, 1024, (x % 36) * 128, (x / 36) * 256, L);
  } else if (x < 288) {
    const int x2 = x - 144;
    gemm_body<128, 0, 0, 0, 1>(Wvt, gn, nullptr, Vt2, nullptr, nullptr, nullptr,
                               4608, 1024, (x2 % 8) * 128, (x2 / 8) * 256, L);
  } else {
    const int x3 = x - 288;
    gemm_body<128, 0, 0, 0, 1>(qn, Wqt, nullptr, Qbf, nullptr, nullptr, nullptr,
                               1024, 512, (x3 % 64) * 128, (x3 / 64) * 256, L);
  }
}

// ---------------------------------------------------------------------------
// MFMA flash attention with swapped-operand softmax.
// Q: (8,1024,1024) bf16; K: (4608,1024) bf16; Vt2: (1024,4608) bf16.
// Block = 64 queries of one (b,h); 4 waves x 16 q.  Per tile:
//   S^T = mfma(K-frag, Q-frag): lane l holds S[key][q] for q=l&15,
//   keys nf*16 + (l>>4)*4 + r  -> row-reduce = 15 in-reg ops + 2 shfl.
//   P^T -> per-wave swizzled LDS -> B-frags; O^T = mfma(V^T-frag, P^T-frag).
// ---------------------------------------------------------------------------
__global__ __launch_bounds__(256) void attn_mfma(const unsigned short* __restrict__ Qb,
                                                 const unsigned short* __restrict__ Kb,
                                                 const unsigned short* __restrict__ Vtb,
                                                 unsigned short* __restrict__ Ob) {
  __shared__ unsigned short Qs[64 * 64];
  __shared__ unsigned short Ks[2][64 * 64];
  __shared__ unsigned short Vs[2][64 * 64];
  __shared__ unsigned short PsT[4][16 * 64];

  const int t = threadIdx.x, w = t >> 6, l = t & 63;
  const int b = blockIdx.z, h = blockIdx.y, q0 = blockIdx.x * 64;
  const int rl = l & 15, kb = l >> 4;

  auto stage64 = [&](unsigned short* lds, const unsigned short* g, int gstride) {
#pragma unroll
    for (int p = 0; p < 2; ++p) {
      int row = p * 32 + w * 8 + (l >> 3);
      const unsigned short* src = g + (size_t)row * gstride + (((l & 7) ^ (row & 7)) * 8);
      gload_lds16(src, lds + p * 2048 + w * 512);
    }
  };

  const unsigned short* Qg = Qb + ((size_t)(b * 1024 + q0) * 1024 + h * 64);
  auto Kg = [&](int kt) { return Kb + ((size_t)(b * 576 + kt * 64) * 1024 + h * 64); };
  auto Vg = [&](int kt) { return Vtb + ((size_t)(h * 64) * 4608 + b * 576 + kt * 64); };

  stage64(Qs, Qg, 1024);
  stage64(Ks[0], Kg(0), 1024);
  stage64(Vs[0], Vg(0), 4608);
  __syncthreads();

  // Q B-side fragments (col = q = rl) for this wave's 16 queries
  bf16x8 qf[2];
  {
    int row = w * 16 + rl;
#pragma unroll
    for (int kf = 0; kf < 2; ++kf)
      qf[kf] = *(const bf16x8*)(Qs + row * 64 + (((kf * 4 + kb) ^ (row & 7)) * 8));
  }

  float m_run = -1e30f, l_run = 0.f;  // per lane: its query q = rl
  f32x4 accOT[4];                     // O^T[d][q]: d = df*16 + kb*4 + r
  f32x4 zz = {0.f, 0.f, 0.f, 0.f};
#pragma unroll
  for (int df = 0; df < 4; ++df) accOT[df] = zz;

  unsigned short* pw = &PsT[w][0];

  for (int kt = 0; kt < 9; ++kt) {
    const int buf = kt & 1;
    if (kt + 1 < 9) {
      stage64(Ks[buf ^ 1], Kg(kt + 1), 1024);
      stage64(Vs[buf ^ 1], Vg(kt + 1), 4608);
    }

    // ---- S^T = K Q^T : accS[nf] rows = keys nf*16+kb*4+r, col = q = rl ----
    f32x4 accS[4];
#pragma unroll
    for (int nf = 0; nf < 4; ++nf) accS[nf] = zz;
#pragma unroll
    for (int nf = 0; nf < 4; ++nf) {
      int row = nf * 16 + rl;
#pragma unroll
      for (int kf = 0; kf < 2; ++kf) {
        bf16x8 kfrag = *(const bf16x8*)(Ks[buf] + row * 64 + (((kf * 4 + kb) ^ (row & 7)) * 8));
        accS[nf] = __builtin_amdgcn_mfma_f32_16x16x32_bf16(kfrag, qf[kf], accS[nf], 0, 0, 0);
      }
    }

    float sv[4][4];
#pragma unroll
    for (int nf = 0; nf < 4; ++nf)
#pragma unroll
      for (int r = 0; r < 4; ++r) sv[nf][r] = accS[nf][r] * 0.125f;

    // ---- online softmax: in-register 16-max + 2 shfl over kb-lanes ----
    float rm = -1e30f;
#pragma unroll
    for (int nf = 0; nf < 4; ++nf)
#pragma unroll
      for (int r = 0; r < 4; ++r) rm = fmaxf(rm, sv[nf][r]);
    rm = fmaxf(rm, __shfl_xor(rm, 16));
    rm = fmaxf(rm, __shfl_xor(rm, 32));
    float mn = fmaxf(m_run, rm);
    float al = __expf(m_run - mn);
    m_run = mn;
    float rs = 0.f;
#pragma unroll
    for (int nf = 0; nf < 4; ++nf)
#pragma unroll
      for (int r = 0; r < 4; ++r) {
        sv[nf][r] = __expf(sv[nf][r] - mn);
        rs += sv[nf][r];
      }
    rs += __shfl_xor(rs, 16);
    rs += __shfl_xor(rs, 32);
    l_run = l_run * al + rs;

    // ---- P^T -> per-wave LDS (row = q, swizzled by key-granule) ----
#pragma unroll
    for (int nf = 0; nf < 4; ++nf)
#pragma unroll
      for (int r = 0; r < 4; ++r) {
        int k = nf * 16 + kb * 4 + r;
        pw[rl * 64 + (((k >> 3) ^ (rl & 7)) * 8) + (k & 7)] = f2b(sv[nf][r]);
      }

    // ---- rescale O^T ----
#pragma unroll
    for (int df = 0; df < 4; ++df)
#pragma unroll
      for (int r = 0; r < 4; ++r) accOT[df][r] *= al;

    WAIT_LGKM0;  // own-wave P writes land before reads (rule 18 fence)

    // ---- O^T += V^T P^T ----
    bf16x8 pf[2];
#pragma unroll
    for (int ks = 0; ks < 2; ++ks)
      pf[ks] = *(const bf16x8*)(pw + rl * 64 + (((ks * 4 + kb) ^ (rl & 7)) * 8));
#pragma unroll
    for (int df = 0; df < 4; ++df) {
      int row = df * 16 + rl;
#pragma unroll
      for (int ks = 0; ks < 2; ++ks) {
        bf16x8 vfrag = *(const bf16x8*)(Vs[buf] + row * 64 + (((ks * 4 + kb) ^ (row & 7)) * 8));
        accOT[df] = __builtin_amdgcn_mfma_f32_16x16x32_bf16(vfrag, pf[ks], accOT[df], 0, 0, 0);
      }
    }

    __syncthreads();  // tile consumed; next iter restages this buffer
  }

  // ---- epilogue: lane owns query q=rl, d-cols df*16+kb*4 .. +3 ----
  float linv = 1.f / l_run;
#pragma unroll
  for (int df = 0; df < 4; ++df) {
    ushort4 ov;
    ov.x = f2b(accOT[df][0] * linv);
    ov.y = f2b(accOT[df][1] * linv);
    ov.z = f2b(accOT[df][2] * linv);
    ov.w = f2b(accOT[df][3] * linv);
    size_t qg = (size_t)(b * 1024 + q0 + w * 16 + rl);
    *(ushort4*)(Ob + qg * 1024 + h * 64 + df * 16 + kb * 4) = ov;
  }
}

// ---------------------------------------------------------------------------
// Launch
// ---------------------------------------------------------------------------
extern "C" void kernel_launch(void* const* d_in, const int* in_sizes, int n_in,
                              void* d_out, int out_size, void* d_ws, size_t ws_size,
                              hipStream_t stream) {
  const float* grid_in = (const float*)d_in[0];
  const float* qpos    = (const float*)d_in[1];
  const float* Wq      = (const float*)d_in[2];
  const float* Wk      = (const float*)d_in[3];
  const float* Wv      = (const float*)d_in[4];
  const float* Wo      = (const float*)d_in[5];
  const float* g_grid  = (const float*)d_in[6];
  const float* b_grid  = (const float*)d_in[7];
  const float* g_q     = (const float*)d_in[8];
  const float* b_q     = (const float*)d_in[9];
  const float* g_mlp   = (const float*)d_in[10];
  const float* b_mlp   = (const float*)d_in[11];
  const float* W1      = (const float*)d_in[12];
  const float* b1      = (const float*)d_in[13];
  const float* W2      = (const float*)d_in[14];
  const float* b2      = (const float*)d_in[15];

  char* ws = (char*)d_ws;
  size_t off = 0;
  auto alloc = [&](size_t bytes) -> void* {
    void* p = ws + off;
    off = (off + bytes + 255) & ~(size_t)255;
    return p;
  };

  unsigned short* Wqt = (unsigned short*)alloc((size_t)1024 * 512 * 2);
  unsigned short* Wkt = (unsigned short*)alloc((size_t)1024 * 1024 * 2);
  unsigned short* Wvt = (unsigned short*)alloc((size_t)1024 * 1024 * 2);
  unsigned short* Wot = (unsigned short*)alloc((size_t)1024 * 1024 * 2);
  unsigned short* W1t = (unsigned short*)alloc((size_t)4096 * 1024 * 2);
  unsigned short* W2t = (unsigned short*)alloc((size_t)1024 * 4096 * 2);
  unsigned short* gn  = (unsigned short*)alloc((size_t)4608 * 1024 * 2);
  unsigned short* qn  = (unsigned short*)alloc((size_t)8192 * 512 * 2);
  unsigned short* Kb  = (unsigned short*)alloc((size_t)4608 * 1024 * 2);
  unsigned short* Qbf = (unsigned short*)alloc((size_t)8192 * 1024 * 2);
  unsigned short* atb = (unsigned short*)alloc((size_t)8192 * 1024 * 2);
  float*          xf  = (float*)alloc((size_t)8192 * 1024 * 4);
  unsigned short* xnb = (unsigned short*)alloc((size_t)8192 * 1024 * 2);
  unsigned short* hb  = (unsigned short*)alloc((size_t)8192 * 4096 * 2);
  unsigned short* Vt2 = hb;  // (1024 x 4608) bf16; dead before W1 writes hb
  (void)ws_size; (void)in_sizes; (void)n_in; (void)out_size;

  // weight transposes (f32 -> bf16, N-major)
  transpose_w<<<dim3(32, 16), 256, 0, stream>>>(Wq, Wqt, 512, 1024);
  transpose_w<<<dim3(32, 32), 256, 0, stream>>>(Wk, Wkt, 1024, 1024);
  transpose_w<<<dim3(32, 32), 256, 0, stream>>>(Wv, Wvt, 1024, 1024);
  transpose_w<<<dim3(32, 32), 256, 0, stream>>>(Wo, Wot, 1024, 1024);
  transpose_w<<<dim3(128, 32), 256, 0, stream>>>(W1, W1t, 1024, 4096);
  transpose_w<<<dim3(32, 128), 256, 0, stream>>>(W2, W2t, 4096, 1024);

  // layernorms
  ln_kernel<<<4608, 256, 0, stream>>>(grid_in, g_grid, b_grid, gn, 1024);
  ln_kernel<<<8192, 256, 0, stream>>>(qpos, g_q, b_q, qn, 512);

  // fused K / V^T / Q projections (one dispatch, 544 blocks)
  kvq_gemm<<<544, 512, 0, stream>>>(gn, Wkt, Kb, Wvt, Vt2, qn, Wqt, Qbf);

  // attention (MFMA, swapped softmax)
  attn_mfma<<<dim3(16, 16, 8), 256, 0, stream>>>(Qbf, Kb, Vt2, atb);

  // x = Q + attn @ Wo   (residual read as bf16)
  gemm256<128, 0, 0, 2, 0><<<dim3(64, 4), 512, 0, stream>>>(atb, Wot, xf, nullptr, nullptr, nullptr, Qbf, 1024, 1024);

  // MLP
  ln_kernel<<<8192, 256, 0, stream>>>(xf, g_mlp, b_mlp, xnb, 1024);
  gemm256<256, 1, 1, 0, 1><<<dim3(32, 16), 512, 0, stream>>>(xnb, W1t, nullptr, hb, b1, nullptr, nullptr, 4096, 1024);
  gemm256<128, 1, 0, 1, 0><<<dim3(64, 4), 512, 0, stream>>>(hb, W2t, (float*)d_out, nullptr, b2, xf, nullptr, 1024, 4096);
}

// Round 8
// 312.582 us; speedup vs baseline: 1.2632x; 1.1244x over previous
//
#include <hip/hip_runtime.h>

// ---------------------------------------------------------------------------
// Types / helpers
// ---------------------------------------------------------------------------
typedef __bf16 bf16x8 __attribute__((ext_vector_type(8)));
typedef float  f32x4  __attribute__((ext_vector_type(4)));
typedef short  s16x8  __attribute__((ext_vector_type(8)));

__device__ __forceinline__ unsigned short f2b(float f) {
  unsigned int u = __float_as_uint(f);
  u += 0x7fffu + ((u >> 16) & 1u);           // round-to-nearest-even
  return (unsigned short)(u >> 16);
}
__device__ __forceinline__ float b2f(unsigned short h) {
  return __uint_as_float(((unsigned int)h) << 16);
}

__device__ __forceinline__ void gload_lds16(const unsigned short* g, unsigned short* l) {
  __builtin_amdgcn_global_load_lds((const __attribute__((address_space(1))) void*)g,
                                   (__attribute__((address_space(3))) void*)l, 16, 0, 0);
}

__device__ __forceinline__ void bar() {
  __builtin_amdgcn_sched_barrier(0);
  asm volatile("" ::: "memory");
  __builtin_amdgcn_s_barrier();
  asm volatile("" ::: "memory");
  __builtin_amdgcn_sched_barrier(0);
}

#define WAIT_LGKM0 do { asm volatile("s_waitcnt lgkmcnt(0)" ::: "memory"); \
                        __builtin_amdgcn_sched_barrier(0); } while (0)

// ---------------------------------------------------------------------------
// Device bodies: weight transpose + layernorm (for the fused prep kernel)
// ---------------------------------------------------------------------------
__device__ __forceinline__ void tw_body(const float* __restrict__ in,
                                        unsigned short* __restrict__ out,
                                        int R, int C, int bx, int by) {
  __shared__ float t[32][33];
  int c0 = bx * 32, r0 = by * 32;
  int tx = threadIdx.x & 31, ty = threadIdx.x >> 5;  // 32 x 8
  for (int i = ty; i < 32; i += 8)
    t[i][tx] = in[(size_t)(r0 + i) * C + (c0 + tx)];
  __syncthreads();
  for (int i = ty; i < 32; i += 8)
    out[(size_t)(c0 + i) * R + (r0 + tx)] = f2b(t[tx][i]);
}

__device__ __forceinline__ void ln_body(const float* __restrict__ in,
                                        const float* __restrict__ g,
                                        const float* __restrict__ b,
                                        unsigned short* __restrict__ out,
                                        int cols, int row) {
  const float* x = in + (size_t)row * cols;
  float s = 0.f, s2 = 0.f;
  for (int c = threadIdx.x * 4; c < cols; c += 1024) {
    float4 v = *(const float4*)(x + c);
    s  += v.x + v.y + v.z + v.w;
    s2 += v.x * v.x + v.y * v.y + v.z * v.z + v.w * v.w;
  }
#pragma unroll
  for (int o = 32; o > 0; o >>= 1) { s += __shfl_down(s, o); s2 += __shfl_down(s2, o); }
  __shared__ float rs[4], rs2[4];
  int w = threadIdx.x >> 6;
  if ((threadIdx.x & 63) == 0) { rs[w] = s; rs2[w] = s2; }
  __syncthreads();
  s  = rs[0] + rs[1] + rs[2] + rs[3];
  s2 = rs2[0] + rs2[1] + rs2[2] + rs2[3];
  float inv  = 1.f / (float)cols;
  float mean = s * inv;
  float var  = s2 * inv - mean * mean;
  float rstd = rsqrtf(var + 1e-5f);
  unsigned short* outp = out + (size_t)row * cols;
  for (int c = threadIdx.x * 4; c < cols; c += 1024) {
    float4 v = *(const float4*)(x + c);
    ushort4 ov;
    ov.x = f2b((v.x - mean) * rstd * g[c + 0] + b[c + 0]);
    ov.y = f2b((v.y - mean) * rstd * g[c + 1] + b[c + 1]);
    ov.z = f2b((v.z - mean) * rstd * g[c + 2] + b[c + 2]);
    ov.w = f2b((v.w - mean) * rstd * g[c + 3] + b[c + 3]);
    *(ushort4*)(outp + c) = ov;
  }
}

// ---------------------------------------------------------------------------
// Fused prep: LN(grid) 4608 + LN(qpos) 8192 + 6 weight transposes 11776
// = 24576 blocks total, role decoded from blockIdx.x.
// ---------------------------------------------------------------------------
__global__ __launch_bounds__(256) void prep_kernel(
    const float* __restrict__ grid_in, const float* __restrict__ g_grid,
    const float* __restrict__ b_grid, unsigned short* __restrict__ gn,
    const float* __restrict__ qpos, const float* __restrict__ g_q,
    const float* __restrict__ b_q, unsigned short* __restrict__ qn,
    const float* __restrict__ Wq, unsigned short* __restrict__ Wqt,
    const float* __restrict__ Wk, unsigned short* __restrict__ Wkt,
    const float* __restrict__ Wv, unsigned short* __restrict__ Wvt,
    const float* __restrict__ Wo, unsigned short* __restrict__ Wot,
    const float* __restrict__ W1, unsigned short* __restrict__ W1t,
    const float* __restrict__ W2, unsigned short* __restrict__ W2t) {
  int x = blockIdx.x;
  if (x < 4608) { ln_body(grid_in, g_grid, b_grid, gn, 1024, x); return; }
  x -= 4608;
  if (x < 8192) { ln_body(qpos, g_q, b_q, qn, 512, x); return; }
  x -= 8192;
  if (x < 512)  { tw_body(Wq, Wqt, 512, 1024, x % 32, x / 32); return; }   // 32 x 16
  x -= 512;
  if (x < 1024) { tw_body(Wk, Wkt, 1024, 1024, x % 32, x / 32); return; }  // 32 x 32
  x -= 1024;
  if (x < 1024) { tw_body(Wv, Wvt, 1024, 1024, x % 32, x / 32); return; }
  x -= 1024;
  if (x < 1024) { tw_body(Wo, Wot, 1024, 1024, x % 32, x / 32); return; }
  x -= 1024;
  if (x < 4096) { tw_body(W1, W1t, 1024, 4096, x % 128, x / 128); return; }  // 128 x 32
  x -= 4096;
  tw_body(W2, W2t, 4096, 1024, x % 32, x / 32);  // 32 x 128
}

// LN3 standalone (depends on xf)
__global__ __launch_bounds__(256) void ln_kernel(const float* __restrict__ in,
                                                 const float* __restrict__ g,
                                                 const float* __restrict__ b,
                                                 unsigned short* __restrict__ out,
                                                 int cols) {
  ln_body(in, g, b, out, cols, blockIdx.x);
}

// ---------------------------------------------------------------------------
// 4-phase counted-vmcnt MFMA GEMM body (round-4-verified, 16x16x32 bf16).
// Tile BM x 256, BK=64, 8 waves (2M x 4N), per-wave output (BM/2) x 64.
// RES: 0=none, 1=f32, 2=bf16.  OUTBF: 1=bf16 out, 0=f32 out.
// L: shared, 2*(BM+256)*64 shorts.  NT must be even (patch reuses L).
// ---------------------------------------------------------------------------
template <int BM, int BIAS, int GELU, int RES, int OUTBF>
__device__ __forceinline__ void gemm_body(const unsigned short* __restrict__ A,
                                          const unsigned short* __restrict__ Bt,
                                          float* __restrict__ Cf,
                                          unsigned short* __restrict__ Cb,
                                          const float* __restrict__ bias,
                                          const float* __restrict__ resf,
                                          const unsigned short* __restrict__ resb,
                                          int N, int K, int m0, int n0,
                                          unsigned short* L) {
  constexpr int MF = BM / 32;   // per-wave M frags (8 or 4)
  constexpr int MH = MF / 2;
  constexpr int LA = BM / 128;  // gload_lds per wave per A-half (2 or 1)
  constexpr int LSTEP = (BM + 256) * 64;
  const int tid = threadIdx.x;
  const int w = tid >> 6, l = tid & 63;
  const int rl = l & 15, kb = l >> 4;
  const int wm = w >> 2, wn = w & 3;
  const int NT = K >> 6;
  const int colsw = ((l & 7) ^ (l >> 3)) * 8;  // pre-swizzled source granule
  const int lrow = l >> 3;

  // half: 0=B0(rows n0..+128), 1=B1, 2=A0(rows m0..+BM/2), 3=A1
  auto stage = [&](int t, int half) {
    if (t >= NT) return;
    unsigned short* base = L + (t & 1) * LSTEP;
    if (half < 2) {
      const unsigned short* g = Bt + (size_t)(n0 + half * 128) * K + t * 64;
#pragma unroll
      for (int j = 0; j < 2; ++j) {
        int row = w * 16 + j * 8;
        gload_lds16(g + (size_t)(row + lrow) * K + colsw,
                    base + BM * 64 + half * 8192 + row * 64);
      }
    } else {
      const int h = half - 2;
      const unsigned short* g = A + (size_t)(m0 + h * (BM / 2)) * K + t * 64;
#pragma unroll
      for (int j = 0; j < LA; ++j) {
        int row = w * (8 * LA) + j * 8;
        gload_lds16(g + (size_t)(row + lrow) * K + colsw,
                    base + h * (BM / 2) * 64 + row * 64);
      }
    }
  };

  f32x4 acc[MF][4];
  f32x4 zz = {0.f, 0.f, 0.f, 0.f};
#pragma unroll
  for (int i = 0; i < MF; ++i)
#pragma unroll
    for (int j = 0; j < 4; ++j) acc[i][j] = zz;

  // prologue: tile0 all 4 halves, tile1 first 3
  stage(0, 0); stage(0, 1); stage(0, 2); stage(0, 3);
  stage(1, 0); stage(1, 1); stage(1, 2);

  const int aoff = wm * (BM / 2) * 64;
  const int boff = BM * 64 + (wn >> 1) * 8192 + (wn & 1) * 64 * 64;

  for (int t = 0; t < NT; ++t) {
    const unsigned short* Lb = L + (t & 1) * LSTEP;
    // ---- gate: tile t fully landed; 3 halves (t+1/t+2) in flight ----
    if (t + 1 < NT) {
      if constexpr (LA == 2) asm volatile("s_waitcnt vmcnt(6)" ::: "memory");
      else                   asm volatile("s_waitcnt vmcnt(5)" ::: "memory");
    } else {
      asm volatile("s_waitcnt vmcnt(0)" ::: "memory");
    }
    __builtin_amdgcn_sched_barrier(0);
    bar();

    bf16x8 af[MH][2], bf[4][2];
    // ---- p1: read all B + lower A; stage (t+1).A1; MFMA q0 ----
#pragma unroll
    for (int mf = 0; mf < MH; ++mf)
#pragma unroll
      for (int kf = 0; kf < 2; ++kf)
        af[mf][kf] = *(const bf16x8*)(Lb + aoff + (mf * 16 + rl) * 64 +
                                      (((kf * 4 + kb) ^ (rl & 7)) * 8));
#pragma unroll
    for (int nf = 0; nf < 4; ++nf)
#pragma unroll
      for (int kf = 0; kf < 2; ++kf)
        bf[nf][kf] = *(const bf16x8*)(Lb + boff + (nf * 16 + rl) * 64 +
                                      (((kf * 4 + kb) ^ (rl & 7)) * 8));
    stage(t + 1, 3);
    WAIT_LGKM0;
    __builtin_amdgcn_s_setprio(1);
#pragma unroll
    for (int mf = 0; mf < MH; ++mf)
#pragma unroll
      for (int nf = 0; nf < 2; ++nf)
#pragma unroll
        for (int kf = 0; kf < 2; ++kf)
          acc[mf][nf] = __builtin_amdgcn_mfma_f32_16x16x32_bf16(af[mf][kf], bf[nf][kf], acc[mf][nf], 0, 0, 0);
    __builtin_amdgcn_s_setprio(0);
    bar();

    // ---- p2: stage (t+2).B0; MFMA q1 ----
    stage(t + 2, 0);
    __builtin_amdgcn_s_setprio(1);
#pragma unroll
    for (int mf = 0; mf < MH; ++mf)
#pragma unroll
      for (int nf = 2; nf < 4; ++nf)
#pragma unroll
        for (int kf = 0; kf < 2; ++kf)
          acc[mf][nf] = __builtin_amdgcn_mfma_f32_16x16x32_bf16(af[mf][kf], bf[nf][kf], acc[mf][nf], 0, 0, 0);
    __builtin_amdgcn_s_setprio(0);
    bar();

    // ---- p3: read upper A; stage (t+2).B1; MFMA q2 ----
#pragma unroll
    for (int mf = 0; mf < MH; ++mf)
#pragma unroll
      for (int kf = 0; kf < 2; ++kf)
        af[mf][kf] = *(const bf16x8*)(Lb + aoff + ((MH + mf) * 16 + rl) * 64 +
                                      (((kf * 4 + kb) ^ (rl & 7)) * 8));
    stage(t + 2, 1);
    WAIT_LGKM0;
    __builtin_amdgcn_s_setprio(1);
#pragma unroll
    for (int mf = 0; mf < MH; ++mf)
#pragma unroll
      for (int nf = 0; nf < 2; ++nf)
#pragma unroll
        for (int kf = 0; kf < 2; ++kf)
          acc[MH + mf][nf] = __builtin_amdgcn_mfma_f32_16x16x32_bf16(af[mf][kf], bf[nf][kf], acc[MH + mf][nf], 0, 0, 0);
    __builtin_amdgcn_s_setprio(0);
    bar();

    // ---- p4: stage (t+2).A0; MFMA q3 ----
    stage(t + 2, 2);
    __builtin_amdgcn_s_setprio(1);
#pragma unroll
    for (int mf = 0; mf < MH; ++mf)
#pragma unroll
      for (int nf = 2; nf < 4; ++nf)
#pragma unroll
        for (int kf = 0; kf < 2; ++kf)
          acc[MH + mf][nf] = __builtin_amdgcn_mfma_f32_16x16x32_bf16(af[mf][kf], bf[nf][kf], acc[MH + mf][nf], 0, 0, 0);
    __builtin_amdgcn_s_setprio(0);
  }

  bar();  // all frag reads done; L free for epilogue patches (NT even)

  // ---- epilogue: per-wave 16x72 patch in LDS, vectorized stores ----
  float bias_v[4];
  if (BIAS) {
#pragma unroll
    for (int nf = 0; nf < 4; ++nf) bias_v[nf] = bias[n0 + wn * 64 + nf * 16 + rl];
  }
  unsigned short* patch  = L + w * (16 * 72);
  float*          patchf = ((float*)L) + w * (16 * 72);

#pragma unroll
  for (int mf = 0; mf < MF; ++mf) {
#pragma unroll
    for (int nf = 0; nf < 4; ++nf) {
#pragma unroll
      for (int r = 0; r < 4; ++r) {
        float v = acc[mf][nf][r];
        if (BIAS) v += bias_v[nf];
        if (GELU) {
          float t2 = 1.5957691f * (v + 0.044715f * v * v * v);  // 2*z
          float e = __expf(fminf(t2, 60.f));
          v = v * e / (e + 1.f);
        }
        int prow = kb * 4 + r, pcol = nf * 16 + rl;
        if (OUTBF) patch[prow * 72 + pcol] = f2b(v);
        else       patchf[prow * 72 + pcol] = v;
      }
    }
    WAIT_LGKM0;  // patch writes visible to own wave before transpose read
    if (OUTBF) {
#pragma unroll
      for (int half = 0; half < 2; ++half) {
        int prow = half * 8 + (l >> 3);
        int pcol = (l & 7) * 8;
        s16x8 vv = *(const s16x8*)(patch + prow * 72 + pcol);
        int grow = m0 + wm * (BM / 2) + mf * 16 + prow;
        int gcol = n0 + wn * 64 + pcol;
        *(s16x8*)(Cb + (size_t)grow * N + gcol) = vv;
      }
    } else {
#pragma unroll
      for (int p = 0; p < 4; ++p) {
        int prow = p * 4 + (l >> 4);
        int pcol = (l & 15) * 4;
        float4 vv = *(const float4*)(patchf + prow * 72 + pcol);
        int grow = m0 + wm * (BM / 2) + mf * 16 + prow;
        int gcol = n0 + wn * 64 + pcol;
        if (RES == 1) {
          float4 rv = *(const float4*)(resf + (size_t)grow * N + gcol);
          vv.x += rv.x; vv.y += rv.y; vv.z += rv.z; vv.w += rv.w;
        }
        if (RES == 2) {
          ushort4 rv = *(const ushort4*)(resb + (size_t)grow * N + gcol);
          vv.x += b2f(rv.x); vv.y += b2f(rv.y); vv.z += b2f(rv.z); vv.w += b2f(rv.w);
        }
        *(float4*)(Cf + (size_t)grow * N + gcol) = vv;
      }
    }
    WAIT_LGKM0;  // reads done before next mf overwrites patch
  }
}

// Generic single-GEMM wrapper
template <int BM, int BIAS, int GELU, int RES, int OUTBF>
__global__ __launch_bounds__(512) void gemm256(const unsigned short* __restrict__ A,
                                               const unsigned short* __restrict__ Bt,
                                               float* __restrict__ Cf,
                                               unsigned short* __restrict__ Cb,
                                               const float* __restrict__ bias,
                                               const float* __restrict__ resf,
                                               const unsigned short* __restrict__ resb,
                                               int N, int K) {
  __shared__ unsigned short L[2 * (BM + 256) * 64];
  gemm_body<BM, BIAS, GELU, RES, OUTBF>(A, Bt, Cf, Cb, bias, resf, resb, N, K,
                                        blockIdx.x * BM, blockIdx.y * 256, L);
}

// ---------------------------------------------------------------------------
// Fused K / V^T / Q projection dispatch: 272 BM=256 blocks (~1.06 rounds).
//   x <  72: K   = gn @ Wk      (M=4608, N=1024, K=1024), 18 x 4
//   x < 144: V^T = Wv^T @ gn^T  (M=1024, N=4608, K=1024), 4 x 18
//   else   : Q   = qn @ Wq      (M=8192, N=1024, K=512),  32 x 4
// ---------------------------------------------------------------------------
__global__ __launch_bounds__(512) void kvq_gemm(const unsigned short* __restrict__ gn,
                                                const unsigned short* __restrict__ Wkt,
                                                unsigned short* __restrict__ Kb,
                                                const unsigned short* __restrict__ Wvt,
                                                unsigned short* __restrict__ Vt2,
                                                const unsigned short* __restrict__ qn,
                                                const unsigned short* __restrict__ Wqt,
                                                unsigned short* __restrict__ Qbf) {
  __shared__ unsigned short L[2 * (256 + 256) * 64];
  const int x = blockIdx.x;
  if (x < 72) {
    gemm_body<256, 0, 0, 0, 1>(gn, Wkt, nullptr, Kb, nullptr, nullptr, nullptr,
                               1024, 1024, (x % 18) * 256, (x / 18) * 256, L);
  } else if (x < 144) {
    const int x2 = x - 72;
    gemm_body<256, 0, 0, 0, 1>(Wvt, gn, nullptr, Vt2, nullptr, nullptr, nullptr,
                               4608, 1024, (x2 % 4) * 256, (x2 / 4) * 256, L);
  } else {
    const int x3 = x - 144;
    gemm_body<256, 0, 0, 0, 1>(qn, Wqt, nullptr, Qbf, nullptr, nullptr, nullptr,
                               1024, 512, (x3 % 32) * 256, (x3 / 32) * 256, L);
  }
}

// ---------------------------------------------------------------------------
// MFMA flash attention with swapped-operand softmax (round-7-verified).
// ---------------------------------------------------------------------------
__global__ __launch_bounds__(256) void attn_mfma(const unsigned short* __restrict__ Qb,
                                                 const unsigned short* __restrict__ Kb,
                                                 const unsigned short* __restrict__ Vtb,
                                                 unsigned short* __restrict__ Ob) {
  __shared__ unsigned short Qs[64 * 64];
  __shared__ unsigned short Ks[2][64 * 64];
  __shared__ unsigned short Vs[2][64 * 64];
  __shared__ unsigned short PsT[4][16 * 64];

  const int t = threadIdx.x, w = t >> 6, l = t & 63;
  const int b = blockIdx.z, h = blockIdx.y, q0 = blockIdx.x * 64;
  const int rl = l & 15, kb = l >> 4;

  auto stage64 = [&](unsigned short* lds, const unsigned short* g, int gstride) {
#pragma unroll
    for (int p = 0; p < 2; ++p) {
      int row = p * 32 + w * 8 + (l >> 3);
      const unsigned short* src = g + (size_t)row * gstride + (((l & 7) ^ (row & 7)) * 8);
      gload_lds16(src, lds + p * 2048 + w * 512);
    }
  };

  const unsigned short* Qg = Qb + ((size_t)(b * 1024 + q0) * 1024 + h * 64);
  auto Kg = [&](int kt) { return Kb + ((size_t)(b * 576 + kt * 64) * 1024 + h * 64); };
  auto Vg = [&](int kt) { return Vtb + ((size_t)(h * 64) * 4608 + b * 576 + kt * 64); };

  stage64(Qs, Qg, 1024);
  stage64(Ks[0], Kg(0), 1024);
  stage64(Vs[0], Vg(0), 4608);
  __syncthreads();

  bf16x8 qf[2];
  {
    int row = w * 16 + rl;
#pragma unroll
    for (int kf = 0; kf < 2; ++kf)
      qf[kf] = *(const bf16x8*)(Qs + row * 64 + (((kf * 4 + kb) ^ (row & 7)) * 8));
  }

  float m_run = -1e30f, l_run = 0.f;
  f32x4 accOT[4];
  f32x4 zz = {0.f, 0.f, 0.f, 0.f};
#pragma unroll
  for (int df = 0; df < 4; ++df) accOT[df] = zz;

  unsigned short* pw = &PsT[w][0];

  for (int kt = 0; kt < 9; ++kt) {
    const int buf = kt & 1;
    if (kt + 1 < 9) {
      stage64(Ks[buf ^ 1], Kg(kt + 1), 1024);
      stage64(Vs[buf ^ 1], Vg(kt + 1), 4608);
    }

    f32x4 accS[4];
#pragma unroll
    for (int nf = 0; nf < 4; ++nf) accS[nf] = zz;
#pragma unroll
    for (int nf = 0; nf < 4; ++nf) {
      int row = nf * 16 + rl;
#pragma unroll
      for (int kf = 0; kf < 2; ++kf) {
        bf16x8 kfrag = *(const bf16x8*)(Ks[buf] + row * 64 + (((kf * 4 + kb) ^ (row & 7)) * 8));
        accS[nf] = __builtin_amdgcn_mfma_f32_16x16x32_bf16(kfrag, qf[kf], accS[nf], 0, 0, 0);
      }
    }

    float sv[4][4];
#pragma unroll
    for (int nf = 0; nf < 4; ++nf)
#pragma unroll
      for (int r = 0; r < 4; ++r) sv[nf][r] = accS[nf][r] * 0.125f;

    float rm = -1e30f;
#pragma unroll
    for (int nf = 0; nf < 4; ++nf)
#pragma unroll
      for (int r = 0; r < 4; ++r) rm = fmaxf(rm, sv[nf][r]);
    rm = fmaxf(rm, __shfl_xor(rm, 16));
    rm = fmaxf(rm, __shfl_xor(rm, 32));
    float mn = fmaxf(m_run, rm);
    float al = __expf(m_run - mn);
    m_run = mn;
    float rs = 0.f;
#pragma unroll
    for (int nf = 0; nf < 4; ++nf)
#pragma unroll
      for (int r = 0; r < 4; ++r) {
        sv[nf][r] = __expf(sv[nf][r] - mn);
        rs += sv[nf][r];
      }
    rs += __shfl_xor(rs, 16);
    rs += __shfl_xor(rs, 32);
    l_run = l_run * al + rs;

#pragma unroll
    for (int nf = 0; nf < 4; ++nf)
#pragma unroll
      for (int r = 0; r < 4; ++r) {
        int k = nf * 16 + kb * 4 + r;
        pw[rl * 64 + (((k >> 3) ^ (rl & 7)) * 8) + (k & 7)] = f2b(sv[nf][r]);
      }

#pragma unroll
    for (int df = 0; df < 4; ++df)
#pragma unroll
      for (int r = 0; r < 4; ++r) accOT[df][r] *= al;

    WAIT_LGKM0;  // own-wave P writes land before reads (rule 18 fence)

    bf16x8 pf[2];
#pragma unroll
    for (int ks = 0; ks < 2; ++ks)
      pf[ks] = *(const bf16x8*)(pw + rl * 64 + (((ks * 4 + kb) ^ (rl & 7)) * 8));
#pragma unroll
    for (int df = 0; df < 4; ++df) {
      int row = df * 16 + rl;
#pragma unroll
      for (int ks = 0; ks < 2; ++ks) {
        bf16x8 vfrag = *(const bf16x8*)(Vs[buf] + row * 64 + (((ks * 4 + kb) ^ (row & 7)) * 8));
        accOT[df] = __builtin_amdgcn_mfma_f32_16x16x32_bf16(vfrag, pf[ks], accOT[df], 0, 0, 0);
      }
    }

    __syncthreads();
  }

  float linv = 1.f / l_run;
#pragma unroll
  for (int df = 0; df < 4; ++df) {
    ushort4 ov;
    ov.x = f2b(accOT[df][0] * linv);
    ov.y = f2b(accOT[df][1] * linv);
    ov.z = f2b(accOT[df][2] * linv);
    ov.w = f2b(accOT[df][3] * linv);
    size_t qg = (size_t)(b * 1024 + q0 + w * 16 + rl);
    *(ushort4*)(Ob + qg * 1024 + h * 64 + df * 16 + kb * 4) = ov;
  }
}

// ---------------------------------------------------------------------------
// Launch
// ---------------------------------------------------------------------------
extern "C" void kernel_launch(void* const* d_in, const int* in_sizes, int n_in,
                              void* d_out, int out_size, void* d_ws, size_t ws_size,
                              hipStream_t stream) {
  const float* grid_in = (const float*)d_in[0];
  const float* qpos    = (const float*)d_in[1];
  const float* Wq      = (const float*)d_in[2];
  const float* Wk      = (const float*)d_in[3];
  const float* Wv      = (const float*)d_in[4];
  const float* Wo      = (const float*)d_in[5];
  const float* g_grid  = (const float*)d_in[6];
  const float* b_grid  = (const float*)d_in[7];
  const float* g_q     = (const float*)d_in[8];
  const float* b_q     = (const float*)d_in[9];
  const float* g_mlp   = (const float*)d_in[10];
  const float* b_mlp   = (const float*)d_in[11];
  const float* W1      = (const float*)d_in[12];
  const float* b1      = (const float*)d_in[13];
  const float* W2      = (const float*)d_in[14];
  const float* b2      = (const float*)d_in[15];

  char* ws = (char*)d_ws;
  size_t off = 0;
  auto alloc = [&](size_t bytes) -> void* {
    void* p = ws + off;
    off = (off + bytes + 255) & ~(size_t)255;
    return p;
  };

  unsigned short* Wqt = (unsigned short*)alloc((size_t)1024 * 512 * 2);
  unsigned short* Wkt = (unsigned short*)alloc((size_t)1024 * 1024 * 2);
  unsigned short* Wvt = (unsigned short*)alloc((size_t)1024 * 1024 * 2);
  unsigned short* Wot = (unsigned short*)alloc((size_t)1024 * 1024 * 2);
  unsigned short* W1t = (unsigned short*)alloc((size_t)4096 * 1024 * 2);
  unsigned short* W2t = (unsigned short*)alloc((size_t)1024 * 4096 * 2);
  unsigned short* gn  = (unsigned short*)alloc((size_t)4608 * 1024 * 2);
  unsigned short* qn  = (unsigned short*)alloc((size_t)8192 * 512 * 2);
  unsigned short* Kb  = (unsigned short*)alloc((size_t)4608 * 1024 * 2);
  unsigned short* Qbf = (unsigned short*)alloc((size_t)8192 * 1024 * 2);
  unsigned short* atb = (unsigned short*)alloc((size_t)8192 * 1024 * 2);
  float*          xf  = (float*)alloc((size_t)8192 * 1024 * 4);
  unsigned short* xnb = (unsigned short*)alloc((size_t)8192 * 1024 * 2);
  unsigned short* hb  = (unsigned short*)alloc((size_t)8192 * 4096 * 2);
  unsigned short* Vt2 = hb;  // (1024 x 4608) bf16; dead before W1 writes hb
  (void)ws_size; (void)in_sizes; (void)n_in; (void)out_size;

  // fused prep: LN(grid), LN(qpos), 6 weight transposes
  prep_kernel<<<24576, 256, 0, stream>>>(grid_in, g_grid, b_grid, gn,
                                         qpos, g_q, b_q, qn,
                                         Wq, Wqt, Wk, Wkt, Wv, Wvt,
                                         Wo, Wot, W1, W1t, W2, W2t);

  // fused K / V^T / Q projections (272 BM=256 blocks)
  kvq_gemm<<<272, 512, 0, stream>>>(gn, Wkt, Kb, Wvt, Vt2, qn, Wqt, Qbf);

  // attention (MFMA, swapped softmax)
  attn_mfma<<<dim3(16, 16, 8), 256, 0, stream>>>(Qbf, Kb, Vt2, atb);

  // x = Q + attn @ Wo   (residual read as bf16)
  gemm256<128, 0, 0, 2, 0><<<dim3(64, 4), 512, 0, stream>>>(atb, Wot, xf, nullptr, nullptr, nullptr, Qbf, 1024, 1024);

  // MLP
  ln_kernel<<<8192, 256, 0, stream>>>(xf, g_mlp, b_mlp, xnb, 1024);
  gemm256<256, 1, 1, 0, 1><<<dim3(32, 16), 512, 0, stream>>>(xnb, W1t, nullptr, hb, b1, nullptr, nullptr, 4096, 1024);
  gemm256<128, 1, 0, 1, 0><<<dim3(64, 4), 512, 0, stream>>>(hb, W2t, (float*)d_out, nullptr, b2, xf, nullptr, 1024, 4096);
}

// Round 10
// 303.103 us; speedup vs baseline: 1.3028x; 1.0313x over previous
//
#include <hip/hip_runtime.h>

// ---------------------------------------------------------------------------
// Types / helpers
// ---------------------------------------------------------------------------
typedef __bf16 bf16x8 __attribute__((ext_vector_type(8)));
typedef float  f32x4  __attribute__((ext_vector_type(4)));
typedef short  s16x8  __attribute__((ext_vector_type(8)));

__device__ __forceinline__ unsigned short f2b(float f) {
  unsigned int u = __float_as_uint(f);
  u += 0x7fffu + ((u >> 16) & 1u);           // round-to-nearest-even
  return (unsigned short)(u >> 16);
}
__device__ __forceinline__ float b2f(unsigned short h) {
  return __uint_as_float(((unsigned int)h) << 16);
}

__device__ __forceinline__ void gload_lds16(const unsigned short* g, unsigned short* l) {
  __builtin_amdgcn_global_load_lds((const __attribute__((address_space(1))) void*)g,
                                   (__attribute__((address_space(3))) void*)l, 16, 0, 0);
}

__device__ __forceinline__ void bar() {
  __builtin_amdgcn_sched_barrier(0);
  asm volatile("" ::: "memory");
  __builtin_amdgcn_s_barrier();
  asm volatile("" ::: "memory");
  __builtin_amdgcn_sched_barrier(0);
}

#define WAIT_LGKM0 do { asm volatile("s_waitcnt lgkmcnt(0)" ::: "memory"); \
                        __builtin_amdgcn_sched_barrier(0); } while (0)

// ---------------------------------------------------------------------------
// Device bodies: weight transpose + layernorm (f32-in and bf16-in variants)
// ---------------------------------------------------------------------------
__device__ __forceinline__ void tw_body(const float* __restrict__ in,
                                        unsigned short* __restrict__ out,
                                        int R, int C, int bx, int by) {
  __shared__ float t[32][33];
  int c0 = bx * 32, r0 = by * 32;
  int tx = threadIdx.x & 31, ty = threadIdx.x >> 5;  // 32 x 8
  for (int i = ty; i < 32; i += 8)
    t[i][tx] = in[(size_t)(r0 + i) * C + (c0 + tx)];
  __syncthreads();
  for (int i = ty; i < 32; i += 8)
    out[(size_t)(c0 + i) * R + (r0 + tx)] = f2b(t[tx][i]);
}

__device__ __forceinline__ void ln_body(const float* __restrict__ in,
                                        const float* __restrict__ g,
                                        const float* __restrict__ b,
                                        unsigned short* __restrict__ out,
                                        int cols, int row) {
  const float* x = in + (size_t)row * cols;
  float s = 0.f, s2 = 0.f;
  for (int c = threadIdx.x * 4; c < cols; c += 1024) {
    float4 v = *(const float4*)(x + c);
    s  += v.x + v.y + v.z + v.w;
    s2 += v.x * v.x + v.y * v.y + v.z * v.z + v.w * v.w;
  }
#pragma unroll
  for (int o = 32; o > 0; o >>= 1) { s += __shfl_down(s, o); s2 += __shfl_down(s2, o); }
  __shared__ float rs[4], rs2[4];
  int w = threadIdx.x >> 6;
  if ((threadIdx.x & 63) == 0) { rs[w] = s; rs2[w] = s2; }
  __syncthreads();
  s  = rs[0] + rs[1] + rs[2] + rs[3];
  s2 = rs2[0] + rs2[1] + rs2[2] + rs2[3];
  float inv  = 1.f / (float)cols;
  float mean = s * inv;
  float var  = s2 * inv - mean * mean;
  float rstd = rsqrtf(var + 1e-5f);
  unsigned short* outp = out + (size_t)row * cols;
  for (int c = threadIdx.x * 4; c < cols; c += 1024) {
    float4 v = *(const float4*)(x + c);
    ushort4 ov;
    ov.x = f2b((v.x - mean) * rstd * g[c + 0] + b[c + 0]);
    ov.y = f2b((v.y - mean) * rstd * g[c + 1] + b[c + 1]);
    ov.z = f2b((v.z - mean) * rstd * g[c + 2] + b[c + 2]);
    ov.w = f2b((v.w - mean) * rstd * g[c + 3] + b[c + 3]);
    *(ushort4*)(outp + c) = ov;
  }
}

// bf16-input LN, cols == 1024 exactly: 256 threads x 4 elements (ushort4).
__device__ __forceinline__ void ln_body_bf16(const unsigned short* __restrict__ in,
                                             const float* __restrict__ g,
                                             const float* __restrict__ b,
                                             unsigned short* __restrict__ out,
                                             int row) {
  const int cols = 1024;
  const unsigned short* x = in + (size_t)row * cols;
  const int c0 = threadIdx.x * 4;  // 256 * 4 == 1024, exact cover
  float xv[4];
  {
    ushort4 v = *(const ushort4*)(x + c0);
    xv[0] = b2f(v.x); xv[1] = b2f(v.y); xv[2] = b2f(v.z); xv[3] = b2f(v.w);
  }
  float s = 0.f, s2 = 0.f;
#pragma unroll
  for (int j = 0; j < 4; ++j) { s += xv[j]; s2 += xv[j] * xv[j]; }
#pragma unroll
  for (int o = 32; o > 0; o >>= 1) { s += __shfl_down(s, o); s2 += __shfl_down(s2, o); }
  __shared__ float rs[4], rs2[4];
  int w = threadIdx.x >> 6;
  if ((threadIdx.x & 63) == 0) { rs[w] = s; rs2[w] = s2; }
  __syncthreads();
  s  = rs[0] + rs[1] + rs[2] + rs[3];
  s2 = rs2[0] + rs2[1] + rs2[2] + rs2[3];
  float inv  = 1.f / (float)cols;
  float mean = s * inv;
  float var  = s2 * inv - mean * mean;
  float rstd = rsqrtf(var + 1e-5f);
  ushort4 ov;
  ov.x = f2b((xv[0] - mean) * rstd * g[c0 + 0] + b[c0 + 0]);
  ov.y = f2b((xv[1] - mean) * rstd * g[c0 + 1] + b[c0 + 1]);
  ov.z = f2b((xv[2] - mean) * rstd * g[c0 + 2] + b[c0 + 2]);
  ov.w = f2b((xv[3] - mean) * rstd * g[c0 + 3] + b[c0 + 3]);
  *(ushort4*)(out + (size_t)row * cols + c0) = ov;
}

// ---------------------------------------------------------------------------
// Fused prep: LN(grid) 4608 + LN(qpos) 8192 + 6 weight transposes 11776
// = 24576 blocks total, role decoded from blockIdx.x.
// ---------------------------------------------------------------------------
__global__ __launch_bounds__(256) void prep_kernel(
    const float* __restrict__ grid_in, const float* __restrict__ g_grid,
    const float* __restrict__ b_grid, unsigned short* __restrict__ gn,
    const float* __restrict__ qpos, const float* __restrict__ g_q,
    const float* __restrict__ b_q, unsigned short* __restrict__ qn,
    const float* __restrict__ Wq, unsigned short* __restrict__ Wqt,
    const float* __restrict__ Wk, unsigned short* __restrict__ Wkt,
    const float* __restrict__ Wv, unsigned short* __restrict__ Wvt,
    const float* __restrict__ Wo, unsigned short* __restrict__ Wot,
    const float* __restrict__ W1, unsigned short* __restrict__ W1t,
    const float* __restrict__ W2, unsigned short* __restrict__ W2t) {
  int x = blockIdx.x;
  if (x < 4608) { ln_body(grid_in, g_grid, b_grid, gn, 1024, x); return; }
  x -= 4608;
  if (x < 8192) { ln_body(qpos, g_q, b_q, qn, 512, x); return; }
  x -= 8192;
  if (x < 512)  { tw_body(Wq, Wqt, 512, 1024, x % 32, x / 32); return; }   // 32 x 16
  x -= 512;
  if (x < 1024) { tw_body(Wk, Wkt, 1024, 1024, x % 32, x / 32); return; }  // 32 x 32
  x -= 1024;
  if (x < 1024) { tw_body(Wv, Wvt, 1024, 1024, x % 32, x / 32); return; }
  x -= 1024;
  if (x < 1024) { tw_body(Wo, Wot, 1024, 1024, x % 32, x / 32); return; }
  x -= 1024;
  if (x < 4096) { tw_body(W1, W1t, 1024, 4096, x % 128, x / 128); return; }  // 128 x 32
  x -= 4096;
  tw_body(W2, W2t, 4096, 1024, x % 32, x / 32);  // 32 x 128
}

// LN3 standalone: bf16 in -> bf16 out (depends on xb)
__global__ __launch_bounds__(256) void ln_kernel_bf16(const unsigned short* __restrict__ in,
                                                      const float* __restrict__ g,
                                                      const float* __restrict__ b,
                                                      unsigned short* __restrict__ out) {
  ln_body_bf16(in, g, b, out, blockIdx.x);
}

// ---------------------------------------------------------------------------
// 4-phase counted-vmcnt MFMA GEMM body (round-4-verified, 16x16x32 bf16).
// Tile BM x 256, BK=64, 8 waves (2M x 4N), per-wave output (BM/2) x 64.
// RES: 0=none, 1=f32, 2=bf16.  OUTBF: 1=bf16 out, 0=f32 out.
// L: shared, 2*(BM+256)*64 shorts.  NT must be even (patch reuses L).
// ---------------------------------------------------------------------------
template <int BM, int BIAS, int GELU, int RES, int OUTBF>
__device__ __forceinline__ void gemm_body(const unsigned short* __restrict__ A,
                                          const unsigned short* __restrict__ Bt,
                                          float* __restrict__ Cf,
                                          unsigned short* __restrict__ Cb,
                                          const float* __restrict__ bias,
                                          const float* __restrict__ resf,
                                          const unsigned short* __restrict__ resb,
                                          int N, int K, int m0, int n0,
                                          unsigned short* L) {
  constexpr int MF = BM / 32;   // per-wave M frags (8 or 4)
  constexpr int MH = MF / 2;
  constexpr int LA = BM / 128;  // gload_lds per wave per A-half (2 or 1)
  constexpr int LSTEP = (BM + 256) * 64;
  const int tid = threadIdx.x;
  const int w = tid >> 6, l = tid & 63;
  const int rl = l & 15, kb = l >> 4;
  const int wm = w >> 2, wn = w & 3;
  const int NT = K >> 6;
  const int colsw = ((l & 7) ^ (l >> 3)) * 8;  // pre-swizzled source granule
  const int lrow = l >> 3;

  // half: 0=B0(rows n0..+128), 1=B1, 2=A0(rows m0..+BM/2), 3=A1
  auto stage = [&](int t, int half) {
    if (t >= NT) return;
    unsigned short* base = L + (t & 1) * LSTEP;
    if (half < 2) {
      const unsigned short* g = Bt + (size_t)(n0 + half * 128) * K + t * 64;
#pragma unroll
      for (int j = 0; j < 2; ++j) {
        int row = w * 16 + j * 8;
        gload_lds16(g + (size_t)(row + lrow) * K + colsw,
                    base + BM * 64 + half * 8192 + row * 64);
      }
    } else {
      const int h = half - 2;
      const unsigned short* g = A + (size_t)(m0 + h * (BM / 2)) * K + t * 64;
#pragma unroll
      for (int j = 0; j < LA; ++j) {
        int row = w * (8 * LA) + j * 8;
        gload_lds16(g + (size_t)(row + lrow) * K + colsw,
                    base + h * (BM / 2) * 64 + row * 64);
      }
    }
  };

  f32x4 acc[MF][4];
  f32x4 zz = {0.f, 0.f, 0.f, 0.f};
#pragma unroll
  for (int i = 0; i < MF; ++i)
#pragma unroll
    for (int j = 0; j < 4; ++j) acc[i][j] = zz;

  // prologue: tile0 all 4 halves, tile1 first 3
  stage(0, 0); stage(0, 1); stage(0, 2); stage(0, 3);
  stage(1, 0); stage(1, 1); stage(1, 2);

  const int aoff = wm * (BM / 2) * 64;
  const int boff = BM * 64 + (wn >> 1) * 8192 + (wn & 1) * 64 * 64;

  for (int t = 0; t < NT; ++t) {
    const unsigned short* Lb = L + (t & 1) * LSTEP;
    // ---- gate: tile t fully landed; 3 halves (t+1/t+2) in flight ----
    if (t + 1 < NT) {
      if constexpr (LA == 2) asm volatile("s_waitcnt vmcnt(6)" ::: "memory");
      else                   asm volatile("s_waitcnt vmcnt(5)" ::: "memory");
    } else {
      asm volatile("s_waitcnt vmcnt(0)" ::: "memory");
    }
    __builtin_amdgcn_sched_barrier(0);
    bar();

    bf16x8 af[MH][2], bf[4][2];
    // ---- p1: read all B + lower A; stage (t+1).A1; MFMA q0 ----
#pragma unroll
    for (int mf = 0; mf < MH; ++mf)
#pragma unroll
      for (int kf = 0; kf < 2; ++kf)
        af[mf][kf] = *(const bf16x8*)(Lb + aoff + (mf * 16 + rl) * 64 +
                                      (((kf * 4 + kb) ^ (rl & 7)) * 8));
#pragma unroll
    for (int nf = 0; nf < 4; ++nf)
#pragma unroll
      for (int kf = 0; kf < 2; ++kf)
        bf[nf][kf] = *(const bf16x8*)(Lb + boff + (nf * 16 + rl) * 64 +
                                      (((kf * 4 + kb) ^ (rl & 7)) * 8));
    stage(t + 1, 3);
    WAIT_LGKM0;
    __builtin_amdgcn_s_setprio(1);
#pragma unroll
    for (int mf = 0; mf < MH; ++mf)
#pragma unroll
      for (int nf = 0; nf < 2; ++nf)
#pragma unroll
        for (int kf = 0; kf < 2; ++kf)
          acc[mf][nf] = __builtin_amdgcn_mfma_f32_16x16x32_bf16(af[mf][kf], bf[nf][kf], acc[mf][nf], 0, 0, 0);
    __builtin_amdgcn_s_setprio(0);
    bar();

    // ---- p2: stage (t+2).B0; MFMA q1 ----
    stage(t + 2, 0);
    __builtin_amdgcn_s_setprio(1);
#pragma unroll
    for (int mf = 0; mf < MH; ++mf)
#pragma unroll
      for (int nf = 2; nf < 4; ++nf)
#pragma unroll
        for (int kf = 0; kf < 2; ++kf)
          acc[mf][nf] = __builtin_amdgcn_mfma_f32_16x16x32_bf16(af[mf][kf], bf[nf][kf], acc[mf][nf], 0, 0, 0);
    __builtin_amdgcn_s_setprio(0);
    bar();

    // ---- p3: read upper A; stage (t+2).B1; MFMA q2 ----
#pragma unroll
    for (int mf = 0; mf < MH; ++mf)
#pragma unroll
      for (int kf = 0; kf < 2; ++kf)
        af[mf][kf] = *(const bf16x8*)(Lb + aoff + ((MH + mf) * 16 + rl) * 64 +
                                      (((kf * 4 + kb) ^ (rl & 7)) * 8));
    stage(t + 2, 1);
    WAIT_LGKM0;
    __builtin_amdgcn_s_setprio(1);
#pragma unroll
    for (int mf = 0; mf < MH; ++mf)
#pragma unroll
      for (int nf = 0; nf < 2; ++nf)
#pragma unroll
        for (int kf = 0; kf < 2; ++kf)
          acc[MH + mf][nf] = __builtin_amdgcn_mfma_f32_16x16x32_bf16(af[mf][kf], bf[nf][kf], acc[MH + mf][nf], 0, 0, 0);
    __builtin_amdgcn_s_setprio(0);
    bar();

    // ---- p4: stage (t+2).A0; MFMA q3 ----
    stage(t + 2, 2);
    __builtin_amdgcn_s_setprio(1);
#pragma unroll
    for (int mf = 0; mf < MH; ++mf)
#pragma unroll
      for (int nf = 2; nf < 4; ++nf)
#pragma unroll
        for (int kf = 0; kf < 2; ++kf)
          acc[MH + mf][nf] = __builtin_amdgcn_mfma_f32_16x16x32_bf16(af[mf][kf], bf[nf][kf], acc[MH + mf][nf], 0, 0, 0);
    __builtin_amdgcn_s_setprio(0);
  }

  bar();  // all frag reads done; L free for epilogue patches (NT even)

  // ---- epilogue: per-wave 16x72 patch in LDS, vectorized stores ----
  float bias_v[4];
  if (BIAS) {
#pragma unroll
    for (int nf = 0; nf < 4; ++nf) bias_v[nf] = bias[n0 + wn * 64 + nf * 16 + rl];
  }
  unsigned short* patch  = L + w * (16 * 72);
  float*          patchf = ((float*)L) + w * (16 * 72);

#pragma unroll
  for (int mf = 0; mf < MF; ++mf) {
#pragma unroll
    for (int nf = 0; nf < 4; ++nf) {
#pragma unroll
      for (int r = 0; r < 4; ++r) {
        float v = acc[mf][nf][r];
        if (BIAS) v += bias_v[nf];
        if (GELU) {
          float t2 = 1.5957691f * (v + 0.044715f * v * v * v);  // 2*z
          float e = __expf(fminf(t2, 60.f));
          v = v * e / (e + 1.f);
        }
        int prow = kb * 4 + r, pcol = nf * 16 + rl;
        if (OUTBF) patch[prow * 72 + pcol] = f2b(v);
        else       patchf[prow * 72 + pcol] = v;
      }
    }
    WAIT_LGKM0;  // patch writes visible to own wave before transpose read
    if (OUTBF) {
#pragma unroll
      for (int half = 0; half < 2; ++half) {
        int prow = half * 8 + (l >> 3);
        int pcol = (l & 7) * 8;
        s16x8 vv = *(const s16x8*)(patch + prow * 72 + pcol);
        int grow = m0 + wm * (BM / 2) + mf * 16 + prow;
        int gcol = n0 + wn * 64 + pcol;
        if (RES == 2) {
          s16x8 rv = *(const s16x8*)(resb + (size_t)grow * N + gcol);
#pragma unroll
          for (int j = 0; j < 8; ++j)
            vv[j] = (short)f2b(b2f((unsigned short)vv[j]) + b2f((unsigned short)rv[j]));
        }
        *(s16x8*)(Cb + (size_t)grow * N + gcol) = vv;
      }
    } else {
#pragma unroll
      for (int p = 0; p < 4; ++p) {
        int prow = p * 4 + (l >> 4);
        int pcol = (l & 15) * 4;
        float4 vv = *(const float4*)(patchf + prow * 72 + pcol);
        int grow = m0 + wm * (BM / 2) + mf * 16 + prow;
        int gcol = n0 + wn * 64 + pcol;
        if (RES == 1) {
          float4 rv = *(const float4*)(resf + (size_t)grow * N + gcol);
          vv.x += rv.x; vv.y += rv.y; vv.z += rv.z; vv.w += rv.w;
        }
        if (RES == 2) {
          ushort4 rv = *(const ushort4*)(resb + (size_t)grow * N + gcol);
          vv.x += b2f(rv.x); vv.y += b2f(rv.y); vv.z += b2f(rv.z); vv.w += b2f(rv.w);
        }
        *(float4*)(Cf + (size_t)grow * N + gcol) = vv;
      }
    }
    WAIT_LGKM0;  // reads done before next mf overwrites patch
  }
}

// Generic single-GEMM wrapper
template <int BM, int BIAS, int GELU, int RES, int OUTBF>
__global__ __launch_bounds__(512) void gemm256(const unsigned short* __restrict__ A,
                                               const unsigned short* __restrict__ Bt,
                                               float* __restrict__ Cf,
                                               unsigned short* __restrict__ Cb,
                                               const float* __restrict__ bias,
                                               const float* __restrict__ resf,
                                               const unsigned short* __restrict__ resb,
                                               int N, int K) {
  __shared__ unsigned short L[2 * (BM + 256) * 64];
  gemm_body<BM, BIAS, GELU, RES, OUTBF>(A, Bt, Cf, Cb, bias, resf, resb, N, K,
                                        blockIdx.x * BM, blockIdx.y * 256, L);
}

// ---------------------------------------------------------------------------
// Fused K / V^T / Q projection dispatch: 272 BM=256 blocks (~1.06 rounds).
//   x <  72: K   = gn @ Wk      (M=4608, N=1024, K=1024), 18 x 4
//   x < 144: V^T = Wv^T @ gn^T  (M=1024, N=4608, K=1024), 4 x 18
//   else   : Q   = qn @ Wq      (M=8192, N=1024, K=512),  32 x 4
// ---------------------------------------------------------------------------
__global__ __launch_bounds__(512) void kvq_gemm(const unsigned short* __restrict__ gn,
                                                const unsigned short* __restrict__ Wkt,
                                                unsigned short* __restrict__ Kb,
                                                const unsigned short* __restrict__ Wvt,
                                                unsigned short* __restrict__ Vt2,
                                                const unsigned short* __restrict__ qn,
                                                const unsigned short* __restrict__ Wqt,
                                                unsigned short* __restrict__ Qbf) {
  __shared__ unsigned short L[2 * (256 + 256) * 64];
  const int x = blockIdx.x;
  if (x < 72) {
    gemm_body<256, 0, 0, 0, 1>(gn, Wkt, nullptr, Kb, nullptr, nullptr, nullptr,
                               1024, 1024, (x % 18) * 256, (x / 18) * 256, L);
  } else if (x < 144) {
    const int x2 = x - 72;
    gemm_body<256, 0, 0, 0, 1>(Wvt, gn, nullptr, Vt2, nullptr, nullptr, nullptr,
                               4608, 1024, (x2 % 4) * 256, (x2 / 4) * 256, L);
  } else {
    const int x3 = x - 144;
    gemm_body<256, 0, 0, 0, 1>(qn, Wqt, nullptr, Qbf, nullptr, nullptr, nullptr,
                               1024, 512, (x3 % 32) * 256, (x3 / 32) * 256, L);
  }
}

// ---------------------------------------------------------------------------
// MFMA flash attention with swapped-operand softmax (round-7-verified).
// ---------------------------------------------------------------------------
__global__ __launch_bounds__(256) void attn_mfma(const unsigned short* __restrict__ Qb,
                                                 const unsigned short* __restrict__ Kb,
                                                 const unsigned short* __restrict__ Vtb,
                                                 unsigned short* __restrict__ Ob) {
  __shared__ unsigned short Qs[64 * 64];
  __shared__ unsigned short Ks[2][64 * 64];
  __shared__ unsigned short Vs[2][64 * 64];
  __shared__ unsigned short PsT[4][16 * 64];

  const int t = threadIdx.x, w = t >> 6, l = t & 63;
  const int b = blockIdx.z, h = blockIdx.y, q0 = blockIdx.x * 64;
  const int rl = l & 15, kb = l >> 4;

  auto stage64 = [&](unsigned short* lds, const unsigned short* g, int gstride) {
#pragma unroll
    for (int p = 0; p < 2; ++p) {
      int row = p * 32 + w * 8 + (l >> 3);
      const unsigned short* src = g + (size_t)row * gstride + (((l & 7) ^ (row & 7)) * 8);
      gload_lds16(src, lds + p * 2048 + w * 512);
    }
  };

  const unsigned short* Qg = Qb + ((size_t)(b * 1024 + q0) * 1024 + h * 64);
  auto Kg = [&](int kt) { return Kb + ((size_t)(b * 576 + kt * 64) * 1024 + h * 64); };
  auto Vg = [&](int kt) { return Vtb + ((size_t)(h * 64) * 4608 + b * 576 + kt * 64); };

  stage64(Qs, Qg, 1024);
  stage64(Ks[0], Kg(0), 1024);
  stage64(Vs[0], Vg(0), 4608);
  __syncthreads();

  bf16x8 qf[2];
  {
    int row = w * 16 + rl;
#pragma unroll
    for (int kf = 0; kf < 2; ++kf)
      qf[kf] = *(const bf16x8*)(Qs + row * 64 + (((kf * 4 + kb) ^ (row & 7)) * 8));
  }

  float m_run = -1e30f, l_run = 0.f;
  f32x4 accOT[4];
  f32x4 zz = {0.f, 0.f, 0.f, 0.f};
#pragma unroll
  for (int df = 0; df < 4; ++df) accOT[df] = zz;

  unsigned short* pw = &PsT[w][0];

  for (int kt = 0; kt < 9; ++kt) {
    const int buf = kt & 1;
    if (kt + 1 < 9) {
      stage64(Ks[buf ^ 1], Kg(kt + 1), 1024);
      stage64(Vs[buf ^ 1], Vg(kt + 1), 4608);
    }

    f32x4 accS[4];
#pragma unroll
    for (int nf = 0; nf < 4; ++nf) accS[nf] = zz;
#pragma unroll
    for (int nf = 0; nf < 4; ++nf) {
      int row = nf * 16 + rl;
#pragma unroll
      for (int kf = 0; kf < 2; ++kf) {
        bf16x8 kfrag = *(const bf16x8*)(Ks[buf] + row * 64 + (((kf * 4 + kb) ^ (row & 7)) * 8));
        accS[nf] = __builtin_amdgcn_mfma_f32_16x16x32_bf16(kfrag, qf[kf], accS[nf], 0, 0, 0);
      }
    }

    float sv[4][4];
#pragma unroll
    for (int nf = 0; nf < 4; ++nf)
#pragma unroll
      for (int r = 0; r < 4; ++r) sv[nf][r] = accS[nf][r] * 0.125f;

    float rm = -1e30f;
#pragma unroll
    for (int nf = 0; nf < 4; ++nf)
#pragma unroll
      for (int r = 0; r < 4; ++r) rm = fmaxf(rm, sv[nf][r]);
    rm = fmaxf(rm, __shfl_xor(rm, 16));
    rm = fmaxf(rm, __shfl_xor(rm, 32));
    float mn = fmaxf(m_run, rm);
    float al = __expf(m_run - mn);
    m_run = mn;
    float rs = 0.f;
#pragma unroll
    for (int nf = 0; nf < 4; ++nf)
#pragma unroll
      for (int r = 0; r < 4; ++r) {
        sv[nf][r] = __expf(sv[nf][r] - mn);
        rs += sv[nf][r];
      }
    rs += __shfl_xor(rs, 16);
    rs += __shfl_xor(rs, 32);
    l_run = l_run * al + rs;

#pragma unroll
    for (int nf = 0; nf < 4; ++nf)
#pragma unroll
      for (int r = 0; r < 4; ++r) {
        int k = nf * 16 + kb * 4 + r;
        pw[rl * 64 + (((k >> 3) ^ (rl & 7)) * 8) + (k & 7)] = f2b(sv[nf][r]);
      }

#pragma unroll
    for (int df = 0; df < 4; ++df)
#pragma unroll
      for (int r = 0; r < 4; ++r) accOT[df][r] *= al;

    WAIT_LGKM0;  // own-wave P writes land before reads (rule 18 fence)

    bf16x8 pf[2];
#pragma unroll
    for (int ks = 0; ks < 2; ++ks)
      pf[ks] = *(const bf16x8*)(pw + rl * 64 + (((ks * 4 + kb) ^ (rl & 7)) * 8));
#pragma unroll
    for (int df = 0; df < 4; ++df) {
      int row = df * 16 + rl;
#pragma unroll
      for (int ks = 0; ks < 2; ++ks) {
        bf16x8 vfrag = *(const bf16x8*)(Vs[buf] + row * 64 + (((ks * 4 + kb) ^ (row & 7)) * 8));
        accOT[df] = __builtin_amdgcn_mfma_f32_16x16x32_bf16(vfrag, pf[ks], accOT[df], 0, 0, 0);
      }
    }

    __syncthreads();
  }

  float linv = 1.f / l_run;
#pragma unroll
  for (int df = 0; df < 4; ++df) {
    ushort4 ov;
    ov.x = f2b(accOT[df][0] * linv);
    ov.y = f2b(accOT[df][1] * linv);
    ov.z = f2b(accOT[df][2] * linv);
    ov.w = f2b(accOT[df][3] * linv);
    size_t qg = (size_t)(b * 1024 + q0 + w * 16 + rl);
    *(ushort4*)(Ob + qg * 1024 + h * 64 + df * 16 + kb * 4) = ov;
  }
}

// ---------------------------------------------------------------------------
// Launch
// ---------------------------------------------------------------------------
extern "C" void kernel_launch(void* const* d_in, const int* in_sizes, int n_in,
                              void* d_out, int out_size, void* d_ws, size_t ws_size,
                              hipStream_t stream) {
  const float* grid_in = (const float*)d_in[0];
  const float* qpos    = (const float*)d_in[1];
  const float* Wq      = (const float*)d_in[2];
  const float* Wk      = (const float*)d_in[3];
  const float* Wv      = (const float*)d_in[4];
  const float* Wo      = (const float*)d_in[5];
  const float* g_grid  = (const float*)d_in[6];
  const float* b_grid  = (const float*)d_in[7];
  const float* g_q     = (const float*)d_in[8];
  const float* b_q     = (const float*)d_in[9];
  const float* g_mlp   = (const float*)d_in[10];
  const float* b_mlp   = (const float*)d_in[11];
  const float* W1      = (const float*)d_in[12];
  const float* b1      = (const float*)d_in[13];
  const float* W2      = (const float*)d_in[14];
  const float* b2      = (const float*)d_in[15];

  char* ws = (char*)d_ws;
  size_t off = 0;
  auto alloc = [&](size_t bytes) -> void* {
    void* p = ws + off;
    off = (off + bytes + 255) & ~(size_t)255;
    return p;
  };

  unsigned short* Wqt = (unsigned short*)alloc((size_t)1024 * 512 * 2);
  unsigned short* Wkt = (unsigned short*)alloc((size_t)1024 * 1024 * 2);
  unsigned short* Wvt = (unsigned short*)alloc((size_t)1024 * 1024 * 2);
  unsigned short* Wot = (unsigned short*)alloc((size_t)1024 * 1024 * 2);
  unsigned short* W1t = (unsigned short*)alloc((size_t)4096 * 1024 * 2);
  unsigned short* W2t = (unsigned short*)alloc((size_t)1024 * 4096 * 2);
  unsigned short* gn  = (unsigned short*)alloc((size_t)4608 * 1024 * 2);
  unsigned short* qn  = (unsigned short*)alloc((size_t)8192 * 512 * 2);
  unsigned short* Kb  = (unsigned short*)alloc((size_t)4608 * 1024 * 2);
  unsigned short* Qbf = (unsigned short*)alloc((size_t)8192 * 1024 * 2);
  unsigned short* atb = (unsigned short*)alloc((size_t)8192 * 1024 * 2);
  unsigned short* xb  = (unsigned short*)alloc((size_t)8192 * 1024 * 2);  // bf16 spine
  unsigned short* xnb = (unsigned short*)alloc((size_t)8192 * 1024 * 2);
  unsigned short* hb  = (unsigned short*)alloc((size_t)8192 * 4096 * 2);
  unsigned short* Vt2 = hb;  // (1024 x 4608) bf16; dead before W1 writes hb
  (void)ws_size; (void)in_sizes; (void)n_in; (void)out_size;

  // fused prep: LN(grid), LN(qpos), 6 weight transposes
  prep_kernel<<<24576, 256, 0, stream>>>(grid_in, g_grid, b_grid, gn,
                                         qpos, g_q, b_q, qn,
                                         Wq, Wqt, Wk, Wkt, Wv, Wvt,
                                         Wo, Wot, W1, W1t, W2, W2t);

  // fused K / V^T / Q projections (272 BM=256 blocks)
  kvq_gemm<<<272, 512, 0, stream>>>(gn, Wkt, Kb, Wvt, Vt2, qn, Wqt, Qbf);

  // attention (MFMA, swapped softmax)
  attn_mfma<<<dim3(16, 16, 8), 256, 0, stream>>>(Qbf, Kb, Vt2, atb);

  // x = Q + attn @ Wo   (bf16 spine: residual bf16, output bf16)
  gemm256<128, 0, 0, 2, 1><<<dim3(64, 4), 512, 0, stream>>>(atb, Wot, nullptr, xb, nullptr, nullptr, Qbf, 1024, 1024);

  // MLP
  ln_kernel_bf16<<<8192, 256, 0, stream>>>(xb, g_mlp, b_mlp, xnb);
  gemm256<256, 1, 1, 0, 1><<<dim3(32, 16), 512, 0, stream>>>(xnb, W1t, nullptr, hb, b1, nullptr, nullptr, 4096, 1024);
  gemm256<128, 1, 0, 2, 0><<<dim3(64, 4), 512, 0, stream>>>(hb, W2t, (float*)d_out, nullptr, b2, nullptr, xb, 1024, 4096);
}